// Round 1
// baseline (1383.499 us; speedup 1.0000x reference)
//
#include <hip/hip_runtime.h>
#include <hip/hip_bf16.h>

// Mamba layer: LN -> in_proj -> conv+silu -> x_proj -> dt_proj+softplus -> scan+gate -> out_proj
// Sizes
#define BATCH 2
#define SEQ   1024
#define DIM   768
#define DI    1536
#define DS    16
#define DCONV 4
#define DTR   48
#define XZW   (2*DI)     // 3072
#define DBCW  (DTR+2*DS) // 80
#define MROWS (BATCH*SEQ) // 2048

__device__ __forceinline__ float sigmoidf_(float x) {
    return 1.f / (1.f + __expf(-x));
}

// ---------------- LayerNorm ----------------
__global__ __launch_bounds__(256) void ln_kernel(const float* __restrict__ x,
                                                 const float* __restrict__ w,
                                                 const float* __restrict__ b,
                                                 float* __restrict__ xn)
{
    __shared__ float red[256];
    int row = blockIdx.x;               // 0..2047
    const float* xr = x + (size_t)row * DIM;
    float* o = xn + (size_t)row * DIM;
    int tid = threadIdx.x;

    float v0 = xr[tid], v1 = xr[tid + 256], v2 = xr[tid + 512];
    red[tid] = v0 + v1 + v2;
    __syncthreads();
    for (int off = 128; off > 0; off >>= 1) {
        if (tid < off) red[tid] += red[tid + off];
        __syncthreads();
    }
    float mu = red[0] * (1.f / DIM);
    __syncthreads();
    float d0 = v0 - mu, d1 = v1 - mu, d2 = v2 - mu;
    red[tid] = d0 * d0 + d1 * d1 + d2 * d2;
    __syncthreads();
    for (int off = 128; off > 0; off >>= 1) {
        if (tid < off) red[tid] += red[tid + off];
        __syncthreads();
    }
    float rstd = rsqrtf(red[0] * (1.f / DIM) + 1e-5f);
    o[tid]       = d0 * rstd * w[tid]       + b[tid];
    o[tid + 256] = d1 * rstd * w[tid + 256] + b[tid + 256];
    o[tid + 512] = d2 * rstd * w[tid + 512] + b[tid + 512];
}

// ---------------- Generic tiled fp32 GEMM: C = act(A @ W^T + bias) ----------------
// A: M x K (lda), W: N x K (ldw), C: M x N (ldc). M % 64 == 0, K % 16 == 0. N guarded.
// act: 0 = none, 1 = softplus
__global__ __launch_bounds__(256) void gemm_nt(const float* __restrict__ A, int lda,
                                               const float* __restrict__ W, int ldw,
                                               float* __restrict__ C, int ldc,
                                               int N, int K,
                                               const float* __restrict__ bias, int act)
{
    __shared__ float As[64][17];
    __shared__ float Ws[64][17];
    int tid = threadIdx.x;
    int tx = tid & 15;   // col group
    int ty = tid >> 4;   // row group
    int m0 = blockIdx.y * 64;
    int n0 = blockIdx.x * 64;

    float acc[4][4] = {};

    for (int k0 = 0; k0 < K; k0 += 16) {
        #pragma unroll
        for (int i = 0; i < 4; ++i) {
            int idx = tid + i * 256;
            int r = idx >> 4, c = idx & 15;
            As[r][c] = A[(size_t)(m0 + r) * lda + k0 + c];
            int nr = n0 + r;
            Ws[r][c] = (nr < N) ? W[(size_t)nr * ldw + k0 + c] : 0.f;
        }
        __syncthreads();
        #pragma unroll
        for (int kk = 0; kk < 16; ++kk) {
            float av[4], wv[4];
            #pragma unroll
            for (int i = 0; i < 4; ++i) av[i] = As[ty * 4 + i][kk];
            #pragma unroll
            for (int j = 0; j < 4; ++j) wv[j] = Ws[tx * 4 + j][kk];
            #pragma unroll
            for (int i = 0; i < 4; ++i)
                #pragma unroll
                for (int j = 0; j < 4; ++j)
                    acc[i][j] += av[i] * wv[j];
        }
        __syncthreads();
    }

    #pragma unroll
    for (int i = 0; i < 4; ++i) {
        int m = m0 + ty * 4 + i;
        #pragma unroll
        for (int j = 0; j < 4; ++j) {
            int n = n0 + tx * 4 + j;
            if (n < N) {
                float v = acc[i][j];
                if (bias) v += bias[n];
                if (act == 1) {
                    // stable softplus: log1p(exp(v))
                    v = (v > 20.f) ? v : log1pf(__expf(v));
                }
                C[(size_t)m * ldc + n] = v;
            }
        }
    }
}

// ---------------- causal depthwise conv + SiLU ----------------
// xm = xz[:, :, 0:DI]; u[b,t,d] = silu(conv_b[d] + sum_k xm[b, t-3+k, d] * conv_w[d,k])
__global__ __launch_bounds__(256) void conv_silu_kernel(const float* __restrict__ xz,
                                                        const float* __restrict__ cw,
                                                        const float* __restrict__ cb,
                                                        float* __restrict__ u)
{
    int idx = blockIdx.x * 256 + threadIdx.x;   // over BATCH*SEQ*DI
    int d = idx % DI;
    int t = (idx / DI) % SEQ;
    int b = idx / (DI * SEQ);

    float acc = cb[d];
    #pragma unroll
    for (int k = 0; k < DCONV; ++k) {
        int tt = t - (DCONV - 1) + k;
        if (tt >= 0) acc += xz[(size_t)(b * SEQ + tt) * XZW + d] * cw[d * DCONV + k];
    }
    u[(size_t)(b * SEQ + t) * DI + d] = acc * sigmoidf_(acc);
}

// ---------------- selective scan + gate ----------------
// One 16-lane group per (b,d): 16 states (n) in lanes. h_t = exp(delta*A)*h + delta*u*B.
// y[b,t,d] = (sum_n h*C) + u*D; y *= silu(z).
__global__ __launch_bounds__(256) void scan_kernel(const float* __restrict__ delta,
                                                   const float* __restrict__ u,
                                                   const float* __restrict__ dbc,
                                                   const float* __restrict__ xz,
                                                   const float* __restrict__ A_log,
                                                   const float* __restrict__ Dp,
                                                   float* __restrict__ y)
{
    int tid = threadIdx.x;
    int n = tid & 15;
    int grp = tid >> 4;                 // 0..15
    int g = blockIdx.x * 16 + grp;      // 0..3071 -> (b,d)
    int b = g / DI;
    int d = g % DI;

    float a = -__expf(A_log[d * DS + n]);
    float Dd = Dp[d];
    float h = 0.f;

    const float* drow = delta + (size_t)b * SEQ * DI;
    const float* urow = u + (size_t)b * SEQ * DI;
    const float* bc   = dbc + (size_t)b * SEQ * DBCW;
    const float* zrow = xz + (size_t)b * SEQ * XZW + DI;
    float* yrow       = y + (size_t)b * SEQ * DI;

    for (int t = 0; t < SEQ; ++t) {
        float dlt = drow[(size_t)t * DI + d];
        float uu  = urow[(size_t)t * DI + d];
        float Bv  = bc[(size_t)t * DBCW + DTR + n];
        float Cv  = bc[(size_t)t * DBCW + DTR + DS + n];
        float dA = __expf(dlt * a);
        h = dA * h + (dlt * uu) * Bv;
        float p = h * Cv;
        p += __shfl_xor(p, 8);
        p += __shfl_xor(p, 4);
        p += __shfl_xor(p, 2);
        p += __shfl_xor(p, 1);
        if (n == 0) {
            float z = zrow[(size_t)t * XZW + d];
            float yv = (p + uu * Dd) * (z * sigmoidf_(z));
            yrow[(size_t)t * DI + d] = yv;
        }
    }
}

extern "C" void kernel_launch(void* const* d_in, const int* in_sizes, int n_in,
                              void* d_out, int out_size, void* d_ws, size_t ws_size,
                              hipStream_t stream) {
    const float* x         = (const float*)d_in[0];
    const float* ln_w      = (const float*)d_in[1];
    const float* ln_b      = (const float*)d_in[2];
    const float* in_proj_w = (const float*)d_in[3];   // (3072, 768)
    const float* conv_w    = (const float*)d_in[4];   // (1536, 4)
    const float* conv_b    = (const float*)d_in[5];   // (1536)
    const float* x_proj_w  = (const float*)d_in[6];   // (80, 1536)
    const float* dt_proj_w = (const float*)d_in[7];   // (1536, 48)
    const float* dt_proj_b = (const float*)d_in[8];   // (1536)
    const float* A_log     = (const float*)d_in[9];   // (1536, 16)
    const float* D_param   = (const float*)d_in[10];  // (1536)
    const float* out_proj_w= (const float*)d_in[11];  // (768, 1536)
    float* out = (float*)d_out;

    float* ws = (float*)d_ws;
    float* xn    = ws;                      // 2048*768
    float* xz    = xn    + (size_t)MROWS * DIM;   // 2048*3072
    float* u     = xz    + (size_t)MROWS * XZW;   // 2048*1536
    float* dbc   = u     + (size_t)MROWS * DI;    // 2048*80
    float* delta = dbc   + (size_t)MROWS * DBCW;  // 2048*1536
    float* y     = delta + (size_t)MROWS * DI;    // 2048*1536

    // 1. LayerNorm
    hipLaunchKernelGGL(ln_kernel, dim3(MROWS), dim3(256), 0, stream, x, ln_w, ln_b, xn);

    // 2. in_proj: xz(2048x3072) = xn(2048x768) @ in_proj_w^T
    hipLaunchKernelGGL(gemm_nt, dim3(XZW / 64, MROWS / 64), dim3(256), 0, stream,
                       xn, DIM, in_proj_w, DIM, xz, XZW, XZW, DIM, (const float*)nullptr, 0);

    // 3. conv + silu -> u
    hipLaunchKernelGGL(conv_silu_kernel, dim3((MROWS * DI) / 256), dim3(256), 0, stream,
                       xz, conv_w, conv_b, u);

    // 4. x_proj: dbc(2048x80) = u @ x_proj_w^T
    hipLaunchKernelGGL(gemm_nt, dim3((DBCW + 63) / 64, MROWS / 64), dim3(256), 0, stream,
                       u, DI, x_proj_w, DI, dbc, DBCW, DBCW, DI, (const float*)nullptr, 0);

    // 5. dt_proj + softplus: delta(2048x1536) = softplus(dbc[:, :48] @ dt_proj_w^T + b)
    hipLaunchKernelGGL(gemm_nt, dim3(DI / 64, MROWS / 64), dim3(256), 0, stream,
                       dbc, DBCW, dt_proj_w, DTR, delta, DI, DI, DTR, dt_proj_b, 1);

    // 6. selective scan + gating -> y
    hipLaunchKernelGGL(scan_kernel, dim3((BATCH * DI) / 16), dim3(256), 0, stream,
                       delta, u, dbc, xz, A_log, D_param, y);

    // 7. out_proj: out(2048x768) = y @ out_proj_w^T
    hipLaunchKernelGGL(gemm_nt, dim3(DIM / 64, MROWS / 64), dim3(256), 0, stream,
                       y, DI, out_proj_w, DI, out, DIM, DIM, DI, (const float*)nullptr, 0);
}

// Round 2
// 790.308 us; speedup vs baseline: 1.7506x; 1.7506x over previous
//
#include <hip/hip_runtime.h>
#include <hip/hip_bf16.h>

// Mamba layer: LN -> in_proj -> conv+silu -> x_proj -> dt_proj+softplus -> scan+gate -> out_proj
// Sizes
#define BATCH 2
#define SEQ   1024
#define DIM   768
#define DI    1536
#define DS    16
#define DCONV 4
#define DTR   48
#define XZW   (2*DI)     // 3072
#define DBCW  (DTR+2*DS) // 80
#define MROWS (BATCH*SEQ) // 2048
#define NCHUNK 16
#define CLEN  (SEQ/NCHUNK) // 64

__device__ __forceinline__ float sigmoidf_(float x) {
    return 1.f / (1.f + __expf(-x));
}

// ---------------- LayerNorm ----------------
__global__ __launch_bounds__(256) void ln_kernel(const float* __restrict__ x,
                                                 const float* __restrict__ w,
                                                 const float* __restrict__ b,
                                                 float* __restrict__ xn)
{
    __shared__ float red[256];
    int row = blockIdx.x;               // 0..2047
    const float* xr = x + (size_t)row * DIM;
    float* o = xn + (size_t)row * DIM;
    int tid = threadIdx.x;

    float v0 = xr[tid], v1 = xr[tid + 256], v2 = xr[tid + 512];
    red[tid] = v0 + v1 + v2;
    __syncthreads();
    for (int off = 128; off > 0; off >>= 1) {
        if (tid < off) red[tid] += red[tid + off];
        __syncthreads();
    }
    float mu = red[0] * (1.f / DIM);
    __syncthreads();
    float d0 = v0 - mu, d1 = v1 - mu, d2 = v2 - mu;
    red[tid] = d0 * d0 + d1 * d1 + d2 * d2;
    __syncthreads();
    for (int off = 128; off > 0; off >>= 1) {
        if (tid < off) red[tid] += red[tid + off];
        __syncthreads();
    }
    float rstd = rsqrtf(red[0] * (1.f / DIM) + 1e-5f);
    o[tid]       = d0 * rstd * w[tid]       + b[tid];
    o[tid + 256] = d1 * rstd * w[tid + 256] + b[tid + 256];
    o[tid + 512] = d2 * rstd * w[tid + 512] + b[tid + 512];
}

// ---------------- Generic tiled fp32 GEMM: C = act(A @ W^T + bias) ----------------
// A: M x K (lda), W: N x K (ldw), C: M x N (ldc). M % 64 == 0, K % 16 == 0. N guarded.
// act: 0 = none, 1 = softplus
__global__ __launch_bounds__(256) void gemm_nt(const float* __restrict__ A, int lda,
                                               const float* __restrict__ W, int ldw,
                                               float* __restrict__ C, int ldc,
                                               int N, int K,
                                               const float* __restrict__ bias, int act)
{
    __shared__ float As[64][17];
    __shared__ float Ws[64][17];
    int tid = threadIdx.x;
    int tx = tid & 15;   // col group
    int ty = tid >> 4;   // row group
    int m0 = blockIdx.y * 64;
    int n0 = blockIdx.x * 64;

    float acc[4][4] = {};

    for (int k0 = 0; k0 < K; k0 += 16) {
        #pragma unroll
        for (int i = 0; i < 4; ++i) {
            int idx = tid + i * 256;
            int r = idx >> 4, c = idx & 15;
            As[r][c] = A[(size_t)(m0 + r) * lda + k0 + c];
            int nr = n0 + r;
            Ws[r][c] = (nr < N) ? W[(size_t)nr * ldw + k0 + c] : 0.f;
        }
        __syncthreads();
        #pragma unroll
        for (int kk = 0; kk < 16; ++kk) {
            float av[4], wv[4];
            #pragma unroll
            for (int i = 0; i < 4; ++i) av[i] = As[ty * 4 + i][kk];
            #pragma unroll
            for (int j = 0; j < 4; ++j) wv[j] = Ws[tx * 4 + j][kk];
            #pragma unroll
            for (int i = 0; i < 4; ++i)
                #pragma unroll
                for (int j = 0; j < 4; ++j)
                    acc[i][j] += av[i] * wv[j];
        }
        __syncthreads();
    }

    #pragma unroll
    for (int i = 0; i < 4; ++i) {
        int m = m0 + ty * 4 + i;
        #pragma unroll
        for (int j = 0; j < 4; ++j) {
            int n = n0 + tx * 4 + j;
            if (n < N) {
                float v = acc[i][j];
                if (bias) v += bias[n];
                if (act == 1) {
                    // stable softplus: log1p(exp(v))
                    v = (v > 20.f) ? v : log1pf(__expf(v));
                }
                C[(size_t)m * ldc + n] = v;
            }
        }
    }
}

// ---------------- causal depthwise conv + SiLU ----------------
// xm = xz[:, :, 0:DI]; u[b,t,d] = silu(conv_b[d] + sum_k xm[b, t-3+k, d] * conv_w[d,k])
__global__ __launch_bounds__(256) void conv_silu_kernel(const float* __restrict__ xz,
                                                        const float* __restrict__ cw,
                                                        const float* __restrict__ cb,
                                                        float* __restrict__ u)
{
    int idx = blockIdx.x * 256 + threadIdx.x;   // over BATCH*SEQ*DI
    int d = idx % DI;
    int t = (idx / DI) % SEQ;
    int b = idx / (DI * SEQ);

    float acc = cb[d];
    #pragma unroll
    for (int k = 0; k < DCONV; ++k) {
        int tt = t - (DCONV - 1) + k;
        if (tt >= 0) acc += xz[(size_t)(b * SEQ + tt) * XZW + d] * cw[d * DCONV + k];
    }
    u[(size_t)(b * SEQ + t) * DI + d] = acc * sigmoidf_(acc);
}

// ---------------- chunked parallel selective scan + gate ----------------
// One block of 256 threads per (b,d). Threads = (chunk 0..15) x (n 0..15).
// Recurrence h_t = dA_t * h_{t-1} + dBu_t is associative: chunk-local (P, S)
// with h_end = P*h_in + S, combined serially across 16 chunks, then replay.
__global__ __launch_bounds__(256) void scan_kernel(const float* __restrict__ delta,
                                                   const float* __restrict__ u,
                                                   const float* __restrict__ dbc,
                                                   const float* __restrict__ xz,
                                                   const float* __restrict__ A_log,
                                                   const float* __restrict__ Dp,
                                                   float* __restrict__ y)
{
    __shared__ float dl_s[SEQ];          // 4 KB: delta column
    __shared__ float uu_s[SEQ];          // 4 KB: u column
    __shared__ float Ps[DS][NCHUNK + 1]; // chunk products, padded vs bank conflicts
    __shared__ float Ss[DS][NCHUNK + 1]; // chunk local sums
    __shared__ float Hin[DS][NCHUNK + 1];// incoming state per chunk

    int tid = threadIdx.x;
    int n = tid & 15;
    int chunk = tid >> 4;               // 0..15
    int g = blockIdx.x;                 // (b,d)
    int b = g / DI;
    int d = g % DI;

    const float* drow = delta + (size_t)b * SEQ * DI + d;
    const float* urow = u     + (size_t)b * SEQ * DI + d;
    const float* bc   = dbc   + (size_t)b * SEQ * DBCW;
    const float* zrow = xz    + (size_t)b * SEQ * XZW + DI + d;
    float* yrow       = y     + (size_t)b * SEQ * DI + d;

    // stage delta/u column into LDS (each element read from global exactly once)
    #pragma unroll
    for (int i = 0; i < SEQ / 256; ++i) {
        int t = tid + i * 256;
        dl_s[t] = drow[(size_t)t * DI];
        uu_s[t] = urow[(size_t)t * DI];
    }

    float a = -__expf(A_log[d * DS + n]);
    int t0 = chunk * CLEN;
    __syncthreads();

    // Phase 1: chunk-local (P, S) with h_in = 0
    float P = 1.f, S = 0.f;
    for (int t = t0; t < t0 + CLEN; ++t) {
        float dlt = dl_s[t];
        float Bv  = bc[(size_t)t * DBCW + DTR + n];
        float dA  = __expf(dlt * a);
        P *= dA;
        S = dA * S + (dlt * uu_s[t]) * Bv;
    }
    Ps[n][chunk] = P;
    Ss[n][chunk] = S;
    __syncthreads();

    // Phase 2: serial combine across chunks (16 threads, 16 steps each)
    if (tid < DS) {
        float h = 0.f;
        #pragma unroll
        for (int c = 0; c < NCHUNK; ++c) {
            Hin[tid][c] = h;
            h = Ps[tid][c] * h + Ss[tid][c];
        }
    }
    __syncthreads();

    // Phase 3: replay chunk with correct h_in, contract with C, gate, write
    float h = Hin[n][chunk];
    float Dd = Dp[d];
    for (int t = t0; t < t0 + CLEN; ++t) {
        float dlt = dl_s[t];
        float uu  = uu_s[t];
        float Bv  = bc[(size_t)t * DBCW + DTR + n];
        float Cv  = bc[(size_t)t * DBCW + DTR + DS + n];
        float dA  = __expf(dlt * a);
        h = dA * h + (dlt * uu) * Bv;
        float p = h * Cv;
        p += __shfl_xor(p, 8);
        p += __shfl_xor(p, 4);
        p += __shfl_xor(p, 2);
        p += __shfl_xor(p, 1);
        if (n == 0) {
            float z = zrow[(size_t)t * XZW];
            float yv = (p + uu * Dd) * (z * sigmoidf_(z));
            yrow[(size_t)t * DI] = yv;
        }
    }
}

extern "C" void kernel_launch(void* const* d_in, const int* in_sizes, int n_in,
                              void* d_out, int out_size, void* d_ws, size_t ws_size,
                              hipStream_t stream) {
    const float* x         = (const float*)d_in[0];
    const float* ln_w      = (const float*)d_in[1];
    const float* ln_b      = (const float*)d_in[2];
    const float* in_proj_w = (const float*)d_in[3];   // (3072, 768)
    const float* conv_w    = (const float*)d_in[4];   // (1536, 4)
    const float* conv_b    = (const float*)d_in[5];   // (1536)
    const float* x_proj_w  = (const float*)d_in[6];   // (80, 1536)
    const float* dt_proj_w = (const float*)d_in[7];   // (1536, 48)
    const float* dt_proj_b = (const float*)d_in[8];   // (1536)
    const float* A_log     = (const float*)d_in[9];   // (1536, 16)
    const float* D_param   = (const float*)d_in[10];  // (1536)
    const float* out_proj_w= (const float*)d_in[11];  // (768, 1536)
    float* out = (float*)d_out;

    float* ws = (float*)d_ws;
    float* xn    = ws;                      // 2048*768
    float* xz    = xn    + (size_t)MROWS * DIM;   // 2048*3072
    float* u     = xz    + (size_t)MROWS * XZW;   // 2048*1536
    float* dbc   = u     + (size_t)MROWS * DI;    // 2048*80
    float* delta = dbc   + (size_t)MROWS * DBCW;  // 2048*1536
    float* y     = delta + (size_t)MROWS * DI;    // 2048*1536

    // 1. LayerNorm
    hipLaunchKernelGGL(ln_kernel, dim3(MROWS), dim3(256), 0, stream, x, ln_w, ln_b, xn);

    // 2. in_proj: xz(2048x3072) = xn(2048x768) @ in_proj_w^T
    hipLaunchKernelGGL(gemm_nt, dim3(XZW / 64, MROWS / 64), dim3(256), 0, stream,
                       xn, DIM, in_proj_w, DIM, xz, XZW, XZW, DIM, (const float*)nullptr, 0);

    // 3. conv + silu -> u
    hipLaunchKernelGGL(conv_silu_kernel, dim3((MROWS * DI) / 256), dim3(256), 0, stream,
                       xz, conv_w, conv_b, u);

    // 4. x_proj: dbc(2048x80) = u @ x_proj_w^T
    hipLaunchKernelGGL(gemm_nt, dim3((DBCW + 63) / 64, MROWS / 64), dim3(256), 0, stream,
                       u, DI, x_proj_w, DI, dbc, DBCW, DBCW, DI, (const float*)nullptr, 0);

    // 5. dt_proj + softplus: delta(2048x1536) = softplus(dbc[:, :48] @ dt_proj_w^T + b)
    hipLaunchKernelGGL(gemm_nt, dim3(DI / 64, MROWS / 64), dim3(256), 0, stream,
                       dbc, DBCW, dt_proj_w, DTR, delta, DI, DI, DTR, dt_proj_b, 1);

    // 6. chunked selective scan + gating -> y  (one block per (b,d))
    hipLaunchKernelGGL(scan_kernel, dim3(BATCH * DI), dim3(256), 0, stream,
                       delta, u, dbc, xz, A_log, D_param, y);

    // 7. out_proj: out(2048x768) = y @ out_proj_w^T
    hipLaunchKernelGGL(gemm_nt, dim3(DIM / 64, MROWS / 64), dim3(256), 0, stream,
                       y, DI, out_proj_w, DI, out, DIM, DIM, DI, (const float*)nullptr, 0);
}

// Round 3
// 428.293 us; speedup vs baseline: 3.2303x; 1.8452x over previous
//
#include <hip/hip_runtime.h>
#include <hip/hip_bf16.h>

// Mamba layer: LN -> in_proj(bf16 MFMA) -> conv+silu -> x_proj -> dt_proj+softplus
//              -> chunked scan+gate -> out_proj(bf16 MFMA)
#define BATCH 2
#define SEQ   1024
#define DIM   768
#define DI    1536
#define DS    16
#define DCONV 4
#define DTR   48
#define XZW   (2*DI)     // 3072
#define DBCW  (DTR+2*DS) // 80
#define MROWS (BATCH*SEQ) // 2048
#define NCHUNK 16
#define CLEN  (SEQ/NCHUNK) // 64

typedef unsigned short ushort_t;
typedef __attribute__((ext_vector_type(8))) short short8;
typedef __attribute__((ext_vector_type(4))) float f32x4;

__device__ __forceinline__ float sigmoidf_(float x) {
    return 1.f / (1.f + __expf(-x));
}

__device__ __forceinline__ ushort_t f2bf(float x) {
    union { float f; unsigned u; } c{x};
    unsigned r = c.u + 0x7FFF + ((c.u >> 16) & 1);   // RNE
    return (ushort_t)(r >> 16);
}

__device__ __forceinline__ void gload16(const void* g, void* lds) {
    __builtin_amdgcn_global_load_lds(
        (const __attribute__((address_space(1))) void*)g,
        (__attribute__((address_space(3))) void*)lds,
        16, 0, 0);
}

// ---------------- fp32 -> bf16 conversion (8 elems/thread) ----------------
__global__ __launch_bounds__(256) void cvt_bf16(const float* __restrict__ in,
                                                ushort_t* __restrict__ out, int n)
{
    int i = (blockIdx.x * 256 + threadIdx.x) * 8;
    if (i >= n) return;
    float4 a = *(const float4*)(in + i);
    float4 b = *(const float4*)(in + i + 4);
    ushort_t o[8] = { f2bf(a.x), f2bf(a.y), f2bf(a.z), f2bf(a.w),
                      f2bf(b.x), f2bf(b.y), f2bf(b.z), f2bf(b.w) };
    *(ushort4*)(out + i)     = *(ushort4*)o;
    *(ushort4*)(out + i + 4) = *(ushort4*)(o + 4);
}

// ---------------- LayerNorm (fp32 in, bf16 out) ----------------
__global__ __launch_bounds__(256) void ln_kernel(const float* __restrict__ x,
                                                 const float* __restrict__ w,
                                                 const float* __restrict__ b,
                                                 ushort_t* __restrict__ xn)
{
    __shared__ float red[256];
    int row = blockIdx.x;               // 0..2047
    const float* xr = x + (size_t)row * DIM;
    ushort_t* o = xn + (size_t)row * DIM;
    int tid = threadIdx.x;

    float v0 = xr[tid], v1 = xr[tid + 256], v2 = xr[tid + 512];
    red[tid] = v0 + v1 + v2;
    __syncthreads();
    for (int off = 128; off > 0; off >>= 1) {
        if (tid < off) red[tid] += red[tid + off];
        __syncthreads();
    }
    float mu = red[0] * (1.f / DIM);
    __syncthreads();
    float d0 = v0 - mu, d1 = v1 - mu, d2 = v2 - mu;
    red[tid] = d0 * d0 + d1 * d1 + d2 * d2;
    __syncthreads();
    for (int off = 128; off > 0; off >>= 1) {
        if (tid < off) red[tid] += red[tid + off];
        __syncthreads();
    }
    float rstd = rsqrtf(red[0] * (1.f / DIM) + 1e-5f);
    o[tid]       = f2bf(d0 * rstd * w[tid]       + b[tid]);
    o[tid + 256] = f2bf(d1 * rstd * w[tid + 256] + b[tid + 256]);
    o[tid + 512] = f2bf(d2 * rstd * w[tid + 512] + b[tid + 512]);
}

// ---------------- bf16 MFMA GEMM: C(MxN fp32) = A(MxK bf16) @ W(NxK bf16)^T ----------
// 128x128 tile, BK=32, 4 waves each computing 64x64 (4x4 frags of 16x16x32).
// M,N multiples of 128; K multiple of 32. m97-style global_load_lds staging.
__global__ __launch_bounds__(256) void gemm_bf16(const ushort_t* __restrict__ A,
                                                 const ushort_t* __restrict__ W,
                                                 float* __restrict__ C,
                                                 int N, int K)
{
    __shared__ __align__(16) ushort_t As[128 * 32];
    __shared__ __align__(16) ushort_t Bs[128 * 32];

    int tid = threadIdx.x;
    int wave = tid >> 6, lane = tid & 63;
    int wr = wave >> 1, wc = wave & 1;
    int l15 = lane & 15, kb = lane >> 4;
    int m0 = blockIdx.y * 128, n0 = blockIdx.x * 128;

    f32x4 acc[4][4] = {};

    for (int k0 = 0; k0 < K; k0 += 32) {
        // stage A,B tiles: 8192 B each; thread t moves one 16B chunk per issue.
        #pragma unroll
        for (int i = 0; i < 2; ++i) {
            int cbase = i * 256 + wave * 64;          // wave-uniform chunk base
            int c = cbase + lane;
            int row = c >> 2;                          // 4 chunks (64B) per row
            int col = (c & 3) * 8;                     // bf16 elems
            gload16(A + (size_t)(m0 + row) * K + k0 + col, (char*)As + (size_t)cbase * 16);
            gload16(W + (size_t)(n0 + row) * K + k0 + col, (char*)Bs + (size_t)cbase * 16);
        }
        __syncthreads();   // compiler inserts vmcnt(0) drain

        short8 af[4], bfr[4];
        #pragma unroll
        for (int m = 0; m < 4; ++m)
            af[m] = *(const short8*)&As[(wr * 64 + m * 16 + l15) * 32 + kb * 8];
        #pragma unroll
        for (int n = 0; n < 4; ++n)
            bfr[n] = *(const short8*)&Bs[(wc * 64 + n * 16 + l15) * 32 + kb * 8];

        #pragma unroll
        for (int m = 0; m < 4; ++m)
            #pragma unroll
            for (int n = 0; n < 4; ++n)
                acc[m][n] = __builtin_amdgcn_mfma_f32_16x16x32_bf16(af[m], bfr[n], acc[m][n], 0, 0, 0);

        __syncthreads();
    }

    // epilogue: C/D layout col = lane&15, row = (lane>>4)*4 + reg
    int r0 = m0 + wr * 64 + kb * 4;
    int c0 = n0 + wc * 64 + l15;
    #pragma unroll
    for (int m = 0; m < 4; ++m)
        #pragma unroll
        for (int n = 0; n < 4; ++n) {
            int rr = r0 + m * 16;
            int cc = c0 + n * 16;
            #pragma unroll
            for (int r = 0; r < 4; ++r)
                C[(size_t)(rr + r) * N + cc] = acc[m][n][r];
        }
}

// ---------------- Generic tiled fp32 GEMM: C = act(A @ W^T + bias) ----------------
__global__ __launch_bounds__(256) void gemm_nt(const float* __restrict__ A, int lda,
                                               const float* __restrict__ W, int ldw,
                                               float* __restrict__ C, int ldc,
                                               int N, int K,
                                               const float* __restrict__ bias, int act)
{
    __shared__ float As[64][17];
    __shared__ float Ws[64][17];
    int tid = threadIdx.x;
    int tx = tid & 15;
    int ty = tid >> 4;
    int m0 = blockIdx.y * 64;
    int n0 = blockIdx.x * 64;

    float acc[4][4] = {};

    for (int k0 = 0; k0 < K; k0 += 16) {
        #pragma unroll
        for (int i = 0; i < 4; ++i) {
            int idx = tid + i * 256;
            int r = idx >> 4, c = idx & 15;
            As[r][c] = A[(size_t)(m0 + r) * lda + k0 + c];
            int nr = n0 + r;
            Ws[r][c] = (nr < N) ? W[(size_t)nr * ldw + k0 + c] : 0.f;
        }
        __syncthreads();
        #pragma unroll
        for (int kk = 0; kk < 16; ++kk) {
            float av[4], wv[4];
            #pragma unroll
            for (int i = 0; i < 4; ++i) av[i] = As[ty * 4 + i][kk];
            #pragma unroll
            for (int j = 0; j < 4; ++j) wv[j] = Ws[tx * 4 + j][kk];
            #pragma unroll
            for (int i = 0; i < 4; ++i)
                #pragma unroll
                for (int j = 0; j < 4; ++j)
                    acc[i][j] += av[i] * wv[j];
        }
        __syncthreads();
    }

    #pragma unroll
    for (int i = 0; i < 4; ++i) {
        int m = m0 + ty * 4 + i;
        #pragma unroll
        for (int j = 0; j < 4; ++j) {
            int n = n0 + tx * 4 + j;
            if (n < N) {
                float v = acc[i][j];
                if (bias) v += bias[n];
                if (act == 1) v = (v > 20.f) ? v : log1pf(__expf(v));
                C[(size_t)m * ldc + n] = v;
            }
        }
    }
}

// ---------------- causal depthwise conv + SiLU ----------------
__global__ __launch_bounds__(256) void conv_silu_kernel(const float* __restrict__ xz,
                                                        const float* __restrict__ cw,
                                                        const float* __restrict__ cb,
                                                        float* __restrict__ u)
{
    int idx = blockIdx.x * 256 + threadIdx.x;
    int d = idx % DI;
    int t = (idx / DI) % SEQ;
    int b = idx / (DI * SEQ);

    float acc = cb[d];
    #pragma unroll
    for (int k = 0; k < DCONV; ++k) {
        int tt = t - (DCONV - 1) + k;
        if (tt >= 0) acc += xz[(size_t)(b * SEQ + tt) * XZW + d] * cw[d * DCONV + k];
    }
    u[(size_t)(b * SEQ + t) * DI + d] = acc * sigmoidf_(acc);
}

// ---------------- chunked parallel selective scan + gate (bf16 y out) -------------
__global__ __launch_bounds__(256) void scan_kernel(const float* __restrict__ delta,
                                                   const float* __restrict__ u,
                                                   const float* __restrict__ dbc,
                                                   const float* __restrict__ xz,
                                                   const float* __restrict__ A_log,
                                                   const float* __restrict__ Dp,
                                                   ushort_t* __restrict__ y)
{
    __shared__ float dl_s[SEQ];
    __shared__ float uu_s[SEQ];
    __shared__ float Ps[DS][NCHUNK + 1];
    __shared__ float Ss[DS][NCHUNK + 1];
    __shared__ float Hin[DS][NCHUNK + 1];

    int tid = threadIdx.x;
    int n = tid & 15;
    int chunk = tid >> 4;
    int g = blockIdx.x;
    int b = g / DI;
    int d = g % DI;

    const float* drow = delta + (size_t)b * SEQ * DI + d;
    const float* urow = u     + (size_t)b * SEQ * DI + d;
    const float* bc   = dbc   + (size_t)b * SEQ * DBCW;
    const float* zrow = xz    + (size_t)b * SEQ * XZW + DI + d;
    ushort_t* yrow    = y     + (size_t)b * SEQ * DI + d;

    #pragma unroll
    for (int i = 0; i < SEQ / 256; ++i) {
        int t = tid + i * 256;
        dl_s[t] = drow[(size_t)t * DI];
        uu_s[t] = urow[(size_t)t * DI];
    }

    float a = -__expf(A_log[d * DS + n]);
    int t0 = chunk * CLEN;
    __syncthreads();

    // Phase 1: chunk-local (P,S), h_in = 0
    float P = 1.f, S = 0.f;
    for (int t = t0; t < t0 + CLEN; ++t) {
        float dlt = dl_s[t];
        float Bv  = bc[(size_t)t * DBCW + DTR + n];
        float dA  = __expf(dlt * a);
        P *= dA;
        S = dA * S + (dlt * uu_s[t]) * Bv;
    }
    Ps[n][chunk] = P;
    Ss[n][chunk] = S;
    __syncthreads();

    // Phase 2: serial chunk combine
    if (tid < DS) {
        float h = 0.f;
        #pragma unroll
        for (int c = 0; c < NCHUNK; ++c) {
            Hin[tid][c] = h;
            h = Ps[tid][c] * h + Ss[tid][c];
        }
    }
    __syncthreads();

    // Phase 3: replay with correct h_in, contract C, gate, write bf16
    float h = Hin[n][chunk];
    float Dd = Dp[d];
    for (int t = t0; t < t0 + CLEN; ++t) {
        float dlt = dl_s[t];
        float uu  = uu_s[t];
        float Bv  = bc[(size_t)t * DBCW + DTR + n];
        float Cv  = bc[(size_t)t * DBCW + DTR + DS + n];
        float dA  = __expf(dlt * a);
        h = dA * h + (dlt * uu) * Bv;
        float p = h * Cv;
        p += __shfl_xor(p, 8);
        p += __shfl_xor(p, 4);
        p += __shfl_xor(p, 2);
        p += __shfl_xor(p, 1);
        if (n == 0) {
            float z = zrow[(size_t)t * XZW];
            float yv = (p + uu * Dd) * (z * sigmoidf_(z));
            yrow[(size_t)t * DI] = f2bf(yv);
        }
    }
}

extern "C" void kernel_launch(void* const* d_in, const int* in_sizes, int n_in,
                              void* d_out, int out_size, void* d_ws, size_t ws_size,
                              hipStream_t stream) {
    const float* x         = (const float*)d_in[0];
    const float* ln_w      = (const float*)d_in[1];
    const float* ln_b      = (const float*)d_in[2];
    const float* in_proj_w = (const float*)d_in[3];   // (3072, 768)
    const float* conv_w    = (const float*)d_in[4];   // (1536, 4)
    const float* conv_b    = (const float*)d_in[5];   // (1536)
    const float* x_proj_w  = (const float*)d_in[6];   // (80, 1536)
    const float* dt_proj_w = (const float*)d_in[7];   // (1536, 48)
    const float* dt_proj_b = (const float*)d_in[8];   // (1536)
    const float* A_log     = (const float*)d_in[9];   // (1536, 16)
    const float* D_param   = (const float*)d_in[10];  // (1536)
    const float* out_proj_w= (const float*)d_in[11];  // (768, 1536)
    float* out = (float*)d_out;

    char* ws = (char*)d_ws;
    size_t off = 0;
    auto alloc = [&](size_t bytes) { void* p = ws + off; off += (bytes + 255) & ~255ull; return p; };

    ushort_t* xn_bf   = (ushort_t*)alloc((size_t)MROWS * DIM * 2);
    ushort_t* w_in_bf = (ushort_t*)alloc((size_t)XZW * DIM * 2);
    ushort_t* w_out_bf= (ushort_t*)alloc((size_t)DIM * DI * 2);
    ushort_t* y_bf    = (ushort_t*)alloc((size_t)MROWS * DI * 2);
    float* xz    = (float*)alloc((size_t)MROWS * XZW * 4);
    float* u     = (float*)alloc((size_t)MROWS * DI * 4);
    float* dbc   = (float*)alloc((size_t)MROWS * DBCW * 4);
    float* delta = (float*)alloc((size_t)MROWS * DI * 4);

    // 0. weight conversions
    hipLaunchKernelGGL(cvt_bf16, dim3((XZW * DIM) / 2048), dim3(256), 0, stream,
                       in_proj_w, w_in_bf, XZW * DIM);
    hipLaunchKernelGGL(cvt_bf16, dim3((DIM * DI) / 2048), dim3(256), 0, stream,
                       out_proj_w, w_out_bf, DIM * DI);

    // 1. LayerNorm -> bf16
    hipLaunchKernelGGL(ln_kernel, dim3(MROWS), dim3(256), 0, stream, x, ln_w, ln_b, xn_bf);

    // 2. in_proj (bf16 MFMA): xz(2048x3072) = xn @ in_proj_w^T
    hipLaunchKernelGGL(gemm_bf16, dim3(XZW / 128, MROWS / 128), dim3(256), 0, stream,
                       xn_bf, w_in_bf, xz, XZW, DIM);

    // 3. conv + silu -> u (fp32)
    hipLaunchKernelGGL(conv_silu_kernel, dim3((MROWS * DI) / 256), dim3(256), 0, stream,
                       xz, conv_w, conv_b, u);

    // 4. x_proj (fp32): dbc(2048x80) = u @ x_proj_w^T
    hipLaunchKernelGGL(gemm_nt, dim3((DBCW + 63) / 64, MROWS / 64), dim3(256), 0, stream,
                       u, DI, x_proj_w, DI, dbc, DBCW, DBCW, DI, (const float*)nullptr, 0);

    // 5. dt_proj + softplus (fp32): delta = softplus(dbc[:, :48] @ dt_proj_w^T + b)
    hipLaunchKernelGGL(gemm_nt, dim3(DI / 64, MROWS / 64), dim3(256), 0, stream,
                       dbc, DBCW, dt_proj_w, DTR, delta, DI, DI, DTR, dt_proj_b, 1);

    // 6. chunked scan + gate -> y (bf16)
    hipLaunchKernelGGL(scan_kernel, dim3(BATCH * DI), dim3(256), 0, stream,
                       delta, u, dbc, xz, A_log, D_param, y_bf);

    // 7. out_proj (bf16 MFMA): out(2048x768) = y @ out_proj_w^T
    hipLaunchKernelGGL(gemm_bf16, dim3(DIM / 128, MROWS / 128), dim3(256), 0, stream,
                       y_bf, w_out_bf, out, DIM, DI);
}

// Round 4
// 274.787 us; speedup vs baseline: 5.0348x; 1.5586x over previous
//
#include <hip/hip_runtime.h>
#include <hip/hip_bf16.h>

// Mamba layer: LN -> in_proj(bf16 MFMA) -> conv+silu -> x_proj(fp32 split-K)
//              -> dt_proj+softplus -> chunked scan+gate -> out_proj(bf16 MFMA split-K)
#define BATCH 2
#define SEQ   1024
#define DIM   768
#define DI    1536
#define DS    16
#define DCONV 4
#define DTR   48
#define XZW   (2*DI)     // 3072
#define DBCW  (DTR+2*DS) // 80
#define MROWS (BATCH*SEQ) // 2048
#define NCHUNK 16
#define CLEN  (SEQ/NCHUNK) // 64
#define XP_KS 8          // x_proj split-K slices
#define OP_KS 4          // out_proj split-K slices

typedef unsigned short ushort_t;
typedef __attribute__((ext_vector_type(8))) short short8;
typedef __attribute__((ext_vector_type(4))) float f32x4;

__device__ __forceinline__ float sigmoidf_(float x) {
    return 1.f / (1.f + __expf(-x));
}

__device__ __forceinline__ ushort_t f2bf(float x) {
    union { float f; unsigned u; } c{x};
    unsigned r = c.u + 0x7FFF + ((c.u >> 16) & 1);   // RNE
    return (ushort_t)(r >> 16);
}

__device__ __forceinline__ void gload16(const void* g, void* lds) {
    __builtin_amdgcn_global_load_lds(
        (const __attribute__((address_space(1))) void*)g,
        (__attribute__((address_space(3))) void*)lds,
        16, 0, 0);
}

// ---------------- fp32 -> bf16 conversion (8 elems/thread) ----------------
__global__ __launch_bounds__(256) void cvt_bf16(const float* __restrict__ in,
                                                ushort_t* __restrict__ out, int n)
{
    int i = (blockIdx.x * 256 + threadIdx.x) * 8;
    if (i >= n) return;
    float4 a = *(const float4*)(in + i);
    float4 b = *(const float4*)(in + i + 4);
    ushort_t o[8] = { f2bf(a.x), f2bf(a.y), f2bf(a.z), f2bf(a.w),
                      f2bf(b.x), f2bf(b.y), f2bf(b.z), f2bf(b.w) };
    *(ushort4*)(out + i)     = *(ushort4*)o;
    *(ushort4*)(out + i + 4) = *(ushort4*)(o + 4);
}

// ---------------- split-K partial reduce: out[i] = sum_z part[z][i] (float4) -------
__global__ __launch_bounds__(256) void reduce_sk4(const float4* __restrict__ part,
                                                  float4* __restrict__ out,
                                                  int count4, int nslices)
{
    int i = blockIdx.x * 256 + threadIdx.x;
    if (i >= count4) return;
    float4 s = part[i];
    for (int z = 1; z < nslices; ++z) {
        float4 p = part[(size_t)z * count4 + i];
        s.x += p.x; s.y += p.y; s.z += p.z; s.w += p.w;
    }
    out[i] = s;
}

// ---------------- LayerNorm (fp32 in, bf16 out) ----------------
__global__ __launch_bounds__(256) void ln_kernel(const float* __restrict__ x,
                                                 const float* __restrict__ w,
                                                 const float* __restrict__ b,
                                                 ushort_t* __restrict__ xn)
{
    __shared__ float red[256];
    int row = blockIdx.x;               // 0..2047
    const float* xr = x + (size_t)row * DIM;
    ushort_t* o = xn + (size_t)row * DIM;
    int tid = threadIdx.x;

    float v0 = xr[tid], v1 = xr[tid + 256], v2 = xr[tid + 512];
    red[tid] = v0 + v1 + v2;
    __syncthreads();
    for (int off = 128; off > 0; off >>= 1) {
        if (tid < off) red[tid] += red[tid + off];
        __syncthreads();
    }
    float mu = red[0] * (1.f / DIM);
    __syncthreads();
    float d0 = v0 - mu, d1 = v1 - mu, d2 = v2 - mu;
    red[tid] = d0 * d0 + d1 * d1 + d2 * d2;
    __syncthreads();
    for (int off = 128; off > 0; off >>= 1) {
        if (tid < off) red[tid] += red[tid + off];
        __syncthreads();
    }
    float rstd = rsqrtf(red[0] * (1.f / DIM) + 1e-5f);
    o[tid]       = f2bf(d0 * rstd * w[tid]       + b[tid]);
    o[tid + 256] = f2bf(d1 * rstd * w[tid + 256] + b[tid + 256]);
    o[tid + 512] = f2bf(d2 * rstd * w[tid + 512] + b[tid + 512]);
}

// ---------------- bf16 MFMA GEMM: C(MxN fp32) = A(MxK bf16) @ W(NxK bf16)^T ----------
// 128x128 tile, BK=32, 4 waves each 64x64 (4x4 frags of 16x16x32).
__global__ __launch_bounds__(256) void gemm_bf16(const ushort_t* __restrict__ A,
                                                 const ushort_t* __restrict__ W,
                                                 float* __restrict__ C,
                                                 int N, int K)
{
    __shared__ __align__(16) ushort_t As[128 * 32];
    __shared__ __align__(16) ushort_t Bs[128 * 32];

    int tid = threadIdx.x;
    int wave = tid >> 6, lane = tid & 63;
    int wr = wave >> 1, wc = wave & 1;
    int l15 = lane & 15, kb = lane >> 4;
    int m0 = blockIdx.y * 128, n0 = blockIdx.x * 128;

    f32x4 acc[4][4] = {};

    for (int k0 = 0; k0 < K; k0 += 32) {
        #pragma unroll
        for (int i = 0; i < 2; ++i) {
            int cbase = i * 256 + wave * 64;
            int c = cbase + lane;
            int row = c >> 2;
            int col = (c & 3) * 8;
            gload16(A + (size_t)(m0 + row) * K + k0 + col, (char*)As + (size_t)cbase * 16);
            gload16(W + (size_t)(n0 + row) * K + k0 + col, (char*)Bs + (size_t)cbase * 16);
        }
        __syncthreads();

        short8 af[4], bfr[4];
        #pragma unroll
        for (int m = 0; m < 4; ++m)
            af[m] = *(const short8*)&As[(wr * 64 + m * 16 + l15) * 32 + kb * 8];
        #pragma unroll
        for (int n = 0; n < 4; ++n)
            bfr[n] = *(const short8*)&Bs[(wc * 64 + n * 16 + l15) * 32 + kb * 8];

        #pragma unroll
        for (int m = 0; m < 4; ++m)
            #pragma unroll
            for (int n = 0; n < 4; ++n)
                acc[m][n] = __builtin_amdgcn_mfma_f32_16x16x32_bf16(af[m], bfr[n], acc[m][n], 0, 0, 0);

        __syncthreads();
    }

    int r0 = m0 + wr * 64 + kb * 4;
    int c0 = n0 + wc * 64 + l15;
    #pragma unroll
    for (int m = 0; m < 4; ++m)
        #pragma unroll
        for (int n = 0; n < 4; ++n) {
            int rr = r0 + m * 16;
            int cc = c0 + n * 16;
            #pragma unroll
            for (int r = 0; r < 4; ++r)
                C[(size_t)(rr + r) * N + cc] = acc[m][n][r];
        }
}

// ---- split-K bf16 MFMA GEMM: Cpart[z] = A @ W^T over K-slice z (z = blockIdx.z) ----
__global__ __launch_bounds__(256) void gemm_bf16_sk(const ushort_t* __restrict__ A,
                                                    const ushort_t* __restrict__ W,
                                                    float* __restrict__ Cpart,
                                                    int N, int Ktot, int Kslice, int M)
{
    __shared__ __align__(16) ushort_t As[128 * 32];
    __shared__ __align__(16) ushort_t Bs[128 * 32];

    int tid = threadIdx.x;
    int wave = tid >> 6, lane = tid & 63;
    int wr = wave >> 1, wc = wave & 1;
    int l15 = lane & 15, kb = lane >> 4;
    int m0 = blockIdx.y * 128, n0 = blockIdx.x * 128;
    int kbase = blockIdx.z * Kslice;
    float* C = Cpart + (size_t)blockIdx.z * M * N;

    f32x4 acc[4][4] = {};

    for (int k0 = kbase; k0 < kbase + Kslice; k0 += 32) {
        #pragma unroll
        for (int i = 0; i < 2; ++i) {
            int cbase = i * 256 + wave * 64;
            int c = cbase + lane;
            int row = c >> 2;
            int col = (c & 3) * 8;
            gload16(A + (size_t)(m0 + row) * Ktot + k0 + col, (char*)As + (size_t)cbase * 16);
            gload16(W + (size_t)(n0 + row) * Ktot + k0 + col, (char*)Bs + (size_t)cbase * 16);
        }
        __syncthreads();

        short8 af[4], bfr[4];
        #pragma unroll
        for (int m = 0; m < 4; ++m)
            af[m] = *(const short8*)&As[(wr * 64 + m * 16 + l15) * 32 + kb * 8];
        #pragma unroll
        for (int n = 0; n < 4; ++n)
            bfr[n] = *(const short8*)&Bs[(wc * 64 + n * 16 + l15) * 32 + kb * 8];

        #pragma unroll
        for (int m = 0; m < 4; ++m)
            #pragma unroll
            for (int n = 0; n < 4; ++n)
                acc[m][n] = __builtin_amdgcn_mfma_f32_16x16x32_bf16(af[m], bfr[n], acc[m][n], 0, 0, 0);

        __syncthreads();
    }

    int r0 = m0 + wr * 64 + kb * 4;
    int c0 = n0 + wc * 64 + l15;
    #pragma unroll
    for (int m = 0; m < 4; ++m)
        #pragma unroll
        for (int n = 0; n < 4; ++n) {
            int rr = r0 + m * 16;
            int cc = c0 + n * 16;
            #pragma unroll
            for (int r = 0; r < 4; ++r)
                C[(size_t)(rr + r) * N + cc] = acc[m][n][r];
        }
}

// ---------------- Generic tiled fp32 GEMM: C = act(A @ W^T + bias) ----------------
__global__ __launch_bounds__(256) void gemm_nt(const float* __restrict__ A, int lda,
                                               const float* __restrict__ W, int ldw,
                                               float* __restrict__ C, int ldc,
                                               int N, int K,
                                               const float* __restrict__ bias, int act)
{
    __shared__ float As[64][17];
    __shared__ float Ws[64][17];
    int tid = threadIdx.x;
    int tx = tid & 15;
    int ty = tid >> 4;
    int m0 = blockIdx.y * 64;
    int n0 = blockIdx.x * 64;

    float acc[4][4] = {};

    for (int k0 = 0; k0 < K; k0 += 16) {
        #pragma unroll
        for (int i = 0; i < 4; ++i) {
            int idx = tid + i * 256;
            int r = idx >> 4, c = idx & 15;
            As[r][c] = A[(size_t)(m0 + r) * lda + k0 + c];
            int nr = n0 + r;
            Ws[r][c] = (nr < N) ? W[(size_t)nr * ldw + k0 + c] : 0.f;
        }
        __syncthreads();
        #pragma unroll
        for (int kk = 0; kk < 16; ++kk) {
            float av[4], wv[4];
            #pragma unroll
            for (int i = 0; i < 4; ++i) av[i] = As[ty * 4 + i][kk];
            #pragma unroll
            for (int j = 0; j < 4; ++j) wv[j] = Ws[tx * 4 + j][kk];
            #pragma unroll
            for (int i = 0; i < 4; ++i)
                #pragma unroll
                for (int j = 0; j < 4; ++j)
                    acc[i][j] += av[i] * wv[j];
        }
        __syncthreads();
    }

    #pragma unroll
    for (int i = 0; i < 4; ++i) {
        int m = m0 + ty * 4 + i;
        #pragma unroll
        for (int j = 0; j < 4; ++j) {
            int n = n0 + tx * 4 + j;
            if (n < N) {
                float v = acc[i][j];
                if (bias) v += bias[n];
                if (act == 1) v = (v > 20.f) ? v : log1pf(__expf(v));
                C[(size_t)m * ldc + n] = v;
            }
        }
    }
}

// ---- split-K fp32 GEMM: Cpart[z] = A @ W^T over K-slice z (no bias/act) ----
__global__ __launch_bounds__(256) void gemm_nt_sk(const float* __restrict__ A, int lda,
                                                  const float* __restrict__ W, int ldw,
                                                  float* __restrict__ Cpart, int ldc,
                                                  int N, int Kslice, int M)
{
    __shared__ float As[64][17];
    __shared__ float Ws[64][17];
    int tid = threadIdx.x;
    int tx = tid & 15;
    int ty = tid >> 4;
    int m0 = blockIdx.y * 64;
    int n0 = blockIdx.x * 64;
    int kbase = blockIdx.z * Kslice;
    float* C = Cpart + (size_t)blockIdx.z * M * ldc;

    float acc[4][4] = {};

    for (int k0 = kbase; k0 < kbase + Kslice; k0 += 16) {
        #pragma unroll
        for (int i = 0; i < 4; ++i) {
            int idx = tid + i * 256;
            int r = idx >> 4, c = idx & 15;
            As[r][c] = A[(size_t)(m0 + r) * lda + k0 + c];
            int nr = n0 + r;
            Ws[r][c] = (nr < N) ? W[(size_t)nr * ldw + k0 + c] : 0.f;
        }
        __syncthreads();
        #pragma unroll
        for (int kk = 0; kk < 16; ++kk) {
            float av[4], wv[4];
            #pragma unroll
            for (int i = 0; i < 4; ++i) av[i] = As[ty * 4 + i][kk];
            #pragma unroll
            for (int j = 0; j < 4; ++j) wv[j] = Ws[tx * 4 + j][kk];
            #pragma unroll
            for (int i = 0; i < 4; ++i)
                #pragma unroll
                for (int j = 0; j < 4; ++j)
                    acc[i][j] += av[i] * wv[j];
        }
        __syncthreads();
    }

    #pragma unroll
    for (int i = 0; i < 4; ++i) {
        int m = m0 + ty * 4 + i;
        #pragma unroll
        for (int j = 0; j < 4; ++j) {
            int n = n0 + tx * 4 + j;
            if (n < N)
                C[(size_t)m * ldc + n] = acc[i][j];
        }
    }
}

// ---------------- causal depthwise conv + SiLU ----------------
__global__ __launch_bounds__(256) void conv_silu_kernel(const float* __restrict__ xz,
                                                        const float* __restrict__ cw,
                                                        const float* __restrict__ cb,
                                                        float* __restrict__ u)
{
    int idx = blockIdx.x * 256 + threadIdx.x;
    int d = idx % DI;
    int t = (idx / DI) % SEQ;
    int b = idx / (DI * SEQ);

    float acc = cb[d];
    #pragma unroll
    for (int k = 0; k < DCONV; ++k) {
        int tt = t - (DCONV - 1) + k;
        if (tt >= 0) acc += xz[(size_t)(b * SEQ + tt) * XZW + d] * cw[d * DCONV + k];
    }
    u[(size_t)(b * SEQ + t) * DI + d] = acc * sigmoidf_(acc);
}

// ---------------- chunked parallel selective scan + gate (bf16 y out) -------------
__global__ __launch_bounds__(256) void scan_kernel(const float* __restrict__ delta,
                                                   const float* __restrict__ u,
                                                   const float* __restrict__ dbc,
                                                   const float* __restrict__ xz,
                                                   const float* __restrict__ A_log,
                                                   const float* __restrict__ Dp,
                                                   ushort_t* __restrict__ y)
{
    __shared__ float dl_s[SEQ];
    __shared__ float uu_s[SEQ];
    __shared__ float Ps[DS][NCHUNK + 1];
    __shared__ float Ss[DS][NCHUNK + 1];
    __shared__ float Hin[DS][NCHUNK + 1];

    int tid = threadIdx.x;
    int n = tid & 15;
    int chunk = tid >> 4;
    int g = blockIdx.x;
    int b = g / DI;
    int d = g % DI;

    const float* drow = delta + (size_t)b * SEQ * DI + d;
    const float* urow = u     + (size_t)b * SEQ * DI + d;
    const float* bc   = dbc   + (size_t)b * SEQ * DBCW;
    const float* zrow = xz    + (size_t)b * SEQ * XZW + DI + d;
    ushort_t* yrow    = y     + (size_t)b * SEQ * DI + d;

    #pragma unroll
    for (int i = 0; i < SEQ / 256; ++i) {
        int t = tid + i * 256;
        dl_s[t] = drow[(size_t)t * DI];
        uu_s[t] = urow[(size_t)t * DI];
    }

    float a = -__expf(A_log[d * DS + n]);
    int t0 = chunk * CLEN;
    __syncthreads();

    float P = 1.f, S = 0.f;
    for (int t = t0; t < t0 + CLEN; ++t) {
        float dlt = dl_s[t];
        float Bv  = bc[(size_t)t * DBCW + DTR + n];
        float dA  = __expf(dlt * a);
        P *= dA;
        S = dA * S + (dlt * uu_s[t]) * Bv;
    }
    Ps[n][chunk] = P;
    Ss[n][chunk] = S;
    __syncthreads();

    if (tid < DS) {
        float h = 0.f;
        #pragma unroll
        for (int c = 0; c < NCHUNK; ++c) {
            Hin[tid][c] = h;
            h = Ps[tid][c] * h + Ss[tid][c];
        }
    }
    __syncthreads();

    float h = Hin[n][chunk];
    float Dd = Dp[d];
    for (int t = t0; t < t0 + CLEN; ++t) {
        float dlt = dl_s[t];
        float uu  = uu_s[t];
        float Bv  = bc[(size_t)t * DBCW + DTR + n];
        float Cv  = bc[(size_t)t * DBCW + DTR + DS + n];
        float dA  = __expf(dlt * a);
        h = dA * h + (dlt * uu) * Bv;
        float p = h * Cv;
        p += __shfl_xor(p, 8);
        p += __shfl_xor(p, 4);
        p += __shfl_xor(p, 2);
        p += __shfl_xor(p, 1);
        if (n == 0) {
            float z = zrow[(size_t)t * XZW];
            float yv = (p + uu * Dd) * (z * sigmoidf_(z));
            yrow[(size_t)t * DI] = f2bf(yv);
        }
    }
}

extern "C" void kernel_launch(void* const* d_in, const int* in_sizes, int n_in,
                              void* d_out, int out_size, void* d_ws, size_t ws_size,
                              hipStream_t stream) {
    const float* x         = (const float*)d_in[0];
    const float* ln_w      = (const float*)d_in[1];
    const float* ln_b      = (const float*)d_in[2];
    const float* in_proj_w = (const float*)d_in[3];   // (3072, 768)
    const float* conv_w    = (const float*)d_in[4];   // (1536, 4)
    const float* conv_b    = (const float*)d_in[5];   // (1536)
    const float* x_proj_w  = (const float*)d_in[6];   // (80, 1536)
    const float* dt_proj_w = (const float*)d_in[7];   // (1536, 48)
    const float* dt_proj_b = (const float*)d_in[8];   // (1536)
    const float* A_log     = (const float*)d_in[9];   // (1536, 16)
    const float* D_param   = (const float*)d_in[10];  // (1536)
    const float* out_proj_w= (const float*)d_in[11];  // (768, 1536)
    float* out = (float*)d_out;

    char* ws = (char*)d_ws;
    size_t off = 0;
    auto alloc = [&](size_t bytes) { void* p = ws + off; off += (bytes + 255) & ~255ull; return p; };

    ushort_t* xn_bf   = (ushort_t*)alloc((size_t)MROWS * DIM * 2);
    ushort_t* w_in_bf = (ushort_t*)alloc((size_t)XZW * DIM * 2);
    ushort_t* w_out_bf= (ushort_t*)alloc((size_t)DIM * DI * 2);
    ushort_t* y_bf    = (ushort_t*)alloc((size_t)MROWS * DI * 2);
    float* xz    = (float*)alloc((size_t)MROWS * XZW * 4);
    float* u     = (float*)alloc((size_t)MROWS * DI * 4);
    float* dbc   = (float*)alloc((size_t)MROWS * DBCW * 4);
    float* delta = (float*)alloc((size_t)MROWS * DI * 4);
    float* xpart = (float*)alloc((size_t)XP_KS * MROWS * DBCW * 4);
    float* opart = (float*)alloc((size_t)OP_KS * MROWS * DIM * 4);

    // 0. weight conversions
    hipLaunchKernelGGL(cvt_bf16, dim3((XZW * DIM) / 2048), dim3(256), 0, stream,
                       in_proj_w, w_in_bf, XZW * DIM);
    hipLaunchKernelGGL(cvt_bf16, dim3((DIM * DI) / 2048), dim3(256), 0, stream,
                       out_proj_w, w_out_bf, DIM * DI);

    // 1. LayerNorm -> bf16
    hipLaunchKernelGGL(ln_kernel, dim3(MROWS), dim3(256), 0, stream, x, ln_w, ln_b, xn_bf);

    // 2. in_proj (bf16 MFMA): xz(2048x3072) = xn @ in_proj_w^T
    hipLaunchKernelGGL(gemm_bf16, dim3(XZW / 128, MROWS / 128), dim3(256), 0, stream,
                       xn_bf, w_in_bf, xz, XZW, DIM);

    // 3. conv + silu -> u (fp32)
    hipLaunchKernelGGL(conv_silu_kernel, dim3((MROWS * DI) / 256), dim3(256), 0, stream,
                       xz, conv_w, conv_b, u);

    // 4. x_proj (fp32 split-K): dbc(2048x80) = u @ x_proj_w^T
    hipLaunchKernelGGL(gemm_nt_sk, dim3((DBCW + 63) / 64, MROWS / 64, XP_KS), dim3(256), 0, stream,
                       u, DI, x_proj_w, DI, xpart, DBCW, DBCW, DI / XP_KS, MROWS);
    hipLaunchKernelGGL(reduce_sk4, dim3((MROWS * DBCW / 4 + 255) / 256), dim3(256), 0, stream,
                       (const float4*)xpart, (float4*)dbc, MROWS * DBCW / 4, XP_KS);

    // 5. dt_proj + softplus (fp32): delta = softplus(dbc[:, :48] @ dt_proj_w^T + b)
    hipLaunchKernelGGL(gemm_nt, dim3(DI / 64, MROWS / 64), dim3(256), 0, stream,
                       dbc, DBCW, dt_proj_w, DTR, delta, DI, DI, DTR, dt_proj_b, 1);

    // 6. chunked scan + gate -> y (bf16)
    hipLaunchKernelGGL(scan_kernel, dim3(BATCH * DI), dim3(256), 0, stream,
                       delta, u, dbc, xz, A_log, D_param, y_bf);

    // 7. out_proj (bf16 MFMA split-K): out(2048x768) = y @ out_proj_w^T
    hipLaunchKernelGGL(gemm_bf16_sk, dim3(DIM / 128, MROWS / 128, OP_KS), dim3(256), 0, stream,
                       y_bf, w_out_bf, opart, DIM, DI, DI / OP_KS, MROWS);
    hipLaunchKernelGGL(reduce_sk4, dim3((MROWS * DIM / 4 + 255) / 256), dim3(256), 0, stream,
                       (const float4*)opart, (float4*)out, MROWS * DIM / 4, OP_KS);
}

// Round 5
// 257.900 us; speedup vs baseline: 5.3645x; 1.0655x over previous
//
#include <hip/hip_runtime.h>
#include <hip/hip_bf16.h>

// Mamba layer: LN -> in_proj(bf16 MFMA) -> conv+silu -> x_proj(fp32 split-K)
//              -> dt_proj+softplus -> chunked scan+gate (XCD-swizzled) -> out_proj(bf16 MFMA split-K)
#define BATCH 2
#define SEQ   1024
#define DIM   768
#define DI    1536
#define DS    16
#define DCONV 4
#define DTR   48
#define XZW   (2*DI)     // 3072
#define DBCW  (DTR+2*DS) // 80
#define MROWS (BATCH*SEQ) // 2048
#define NCHUNK 16
#define CLEN  (SEQ/NCHUNK) // 64
#define XP_KS 8          // x_proj split-K slices
#define OP_KS 4          // out_proj split-K slices

typedef unsigned short ushort_t;
typedef __attribute__((ext_vector_type(8))) short short8;
typedef __attribute__((ext_vector_type(4))) float f32x4;

__device__ __forceinline__ float sigmoidf_(float x) {
    return 1.f / (1.f + __expf(-x));
}

__device__ __forceinline__ ushort_t f2bf(float x) {
    union { float f; unsigned u; } c{x};
    unsigned r = c.u + 0x7FFF + ((c.u >> 16) & 1);   // RNE
    return (ushort_t)(r >> 16);
}

__device__ __forceinline__ void gload16(const void* g, void* lds) {
    __builtin_amdgcn_global_load_lds(
        (const __attribute__((address_space(1))) void*)g,
        (__attribute__((address_space(3))) void*)lds,
        16, 0, 0);
}

// ---------------- fp32 -> bf16 conversion (8 elems/thread) ----------------
__global__ __launch_bounds__(256) void cvt_bf16(const float* __restrict__ in,
                                                ushort_t* __restrict__ out, int n)
{
    int i = (blockIdx.x * 256 + threadIdx.x) * 8;
    if (i >= n) return;
    float4 a = *(const float4*)(in + i);
    float4 b = *(const float4*)(in + i + 4);
    ushort_t o[8] = { f2bf(a.x), f2bf(a.y), f2bf(a.z), f2bf(a.w),
                      f2bf(b.x), f2bf(b.y), f2bf(b.z), f2bf(b.w) };
    *(ushort4*)(out + i)     = *(ushort4*)o;
    *(ushort4*)(out + i + 4) = *(ushort4*)(o + 4);
}

// ---------------- split-K partial reduce: out[i] = sum_z part[z][i] (float4) -------
__global__ __launch_bounds__(256) void reduce_sk4(const float4* __restrict__ part,
                                                  float4* __restrict__ out,
                                                  int count4, int nslices)
{
    int i = blockIdx.x * 256 + threadIdx.x;
    if (i >= count4) return;
    float4 s = part[i];
    for (int z = 1; z < nslices; ++z) {
        float4 p = part[(size_t)z * count4 + i];
        s.x += p.x; s.y += p.y; s.z += p.z; s.w += p.w;
    }
    out[i] = s;
}

// ---------------- LayerNorm (fp32 in, bf16 out) ----------------
__global__ __launch_bounds__(256) void ln_kernel(const float* __restrict__ x,
                                                 const float* __restrict__ w,
                                                 const float* __restrict__ b,
                                                 ushort_t* __restrict__ xn)
{
    __shared__ float red[256];
    int row = blockIdx.x;               // 0..2047
    const float* xr = x + (size_t)row * DIM;
    ushort_t* o = xn + (size_t)row * DIM;
    int tid = threadIdx.x;

    float v0 = xr[tid], v1 = xr[tid + 256], v2 = xr[tid + 512];
    red[tid] = v0 + v1 + v2;
    __syncthreads();
    for (int off = 128; off > 0; off >>= 1) {
        if (tid < off) red[tid] += red[tid + off];
        __syncthreads();
    }
    float mu = red[0] * (1.f / DIM);
    __syncthreads();
    float d0 = v0 - mu, d1 = v1 - mu, d2 = v2 - mu;
    red[tid] = d0 * d0 + d1 * d1 + d2 * d2;
    __syncthreads();
    for (int off = 128; off > 0; off >>= 1) {
        if (tid < off) red[tid] += red[tid + off];
        __syncthreads();
    }
    float rstd = rsqrtf(red[0] * (1.f / DIM) + 1e-5f);
    o[tid]       = f2bf(d0 * rstd * w[tid]       + b[tid]);
    o[tid + 256] = f2bf(d1 * rstd * w[tid + 256] + b[tid + 256]);
    o[tid + 512] = f2bf(d2 * rstd * w[tid + 512] + b[tid + 512]);
}

// ---------------- bf16 MFMA GEMM: C(MxN fp32) = A(MxK bf16) @ W(NxK bf16)^T ----------
__global__ __launch_bounds__(256) void gemm_bf16(const ushort_t* __restrict__ A,
                                                 const ushort_t* __restrict__ W,
                                                 float* __restrict__ C,
                                                 int N, int K)
{
    __shared__ __align__(16) ushort_t As[128 * 32];
    __shared__ __align__(16) ushort_t Bs[128 * 32];

    int tid = threadIdx.x;
    int wave = tid >> 6, lane = tid & 63;
    int wr = wave >> 1, wc = wave & 1;
    int l15 = lane & 15, kb = lane >> 4;
    int m0 = blockIdx.y * 128, n0 = blockIdx.x * 128;

    f32x4 acc[4][4] = {};

    for (int k0 = 0; k0 < K; k0 += 32) {
        #pragma unroll
        for (int i = 0; i < 2; ++i) {
            int cbase = i * 256 + wave * 64;
            int c = cbase + lane;
            int row = c >> 2;
            int col = (c & 3) * 8;
            gload16(A + (size_t)(m0 + row) * K + k0 + col, (char*)As + (size_t)cbase * 16);
            gload16(W + (size_t)(n0 + row) * K + k0 + col, (char*)Bs + (size_t)cbase * 16);
        }
        __syncthreads();

        short8 af[4], bfr[4];
        #pragma unroll
        for (int m = 0; m < 4; ++m)
            af[m] = *(const short8*)&As[(wr * 64 + m * 16 + l15) * 32 + kb * 8];
        #pragma unroll
        for (int n = 0; n < 4; ++n)
            bfr[n] = *(const short8*)&Bs[(wc * 64 + n * 16 + l15) * 32 + kb * 8];

        #pragma unroll
        for (int m = 0; m < 4; ++m)
            #pragma unroll
            for (int n = 0; n < 4; ++n)
                acc[m][n] = __builtin_amdgcn_mfma_f32_16x16x32_bf16(af[m], bfr[n], acc[m][n], 0, 0, 0);

        __syncthreads();
    }

    int r0 = m0 + wr * 64 + kb * 4;
    int c0 = n0 + wc * 64 + l15;
    #pragma unroll
    for (int m = 0; m < 4; ++m)
        #pragma unroll
        for (int n = 0; n < 4; ++n) {
            int rr = r0 + m * 16;
            int cc = c0 + n * 16;
            #pragma unroll
            for (int r = 0; r < 4; ++r)
                C[(size_t)(rr + r) * N + cc] = acc[m][n][r];
        }
}

// ---- split-K bf16 MFMA GEMM: Cpart[z] = A @ W^T over K-slice z (z = blockIdx.z) ----
__global__ __launch_bounds__(256) void gemm_bf16_sk(const ushort_t* __restrict__ A,
                                                    const ushort_t* __restrict__ W,
                                                    float* __restrict__ Cpart,
                                                    int N, int Ktot, int Kslice, int M)
{
    __shared__ __align__(16) ushort_t As[128 * 32];
    __shared__ __align__(16) ushort_t Bs[128 * 32];

    int tid = threadIdx.x;
    int wave = tid >> 6, lane = tid & 63;
    int wr = wave >> 1, wc = wave & 1;
    int l15 = lane & 15, kb = lane >> 4;
    int m0 = blockIdx.y * 128, n0 = blockIdx.x * 128;
    int kbase = blockIdx.z * Kslice;
    float* C = Cpart + (size_t)blockIdx.z * M * N;

    f32x4 acc[4][4] = {};

    for (int k0 = kbase; k0 < kbase + Kslice; k0 += 32) {
        #pragma unroll
        for (int i = 0; i < 2; ++i) {
            int cbase = i * 256 + wave * 64;
            int c = cbase + lane;
            int row = c >> 2;
            int col = (c & 3) * 8;
            gload16(A + (size_t)(m0 + row) * Ktot + k0 + col, (char*)As + (size_t)cbase * 16);
            gload16(W + (size_t)(n0 + row) * Ktot + k0 + col, (char*)Bs + (size_t)cbase * 16);
        }
        __syncthreads();

        short8 af[4], bfr[4];
        #pragma unroll
        for (int m = 0; m < 4; ++m)
            af[m] = *(const short8*)&As[(wr * 64 + m * 16 + l15) * 32 + kb * 8];
        #pragma unroll
        for (int n = 0; n < 4; ++n)
            bfr[n] = *(const short8*)&Bs[(wc * 64 + n * 16 + l15) * 32 + kb * 8];

        #pragma unroll
        for (int m = 0; m < 4; ++m)
            #pragma unroll
            for (int n = 0; n < 4; ++n)
                acc[m][n] = __builtin_amdgcn_mfma_f32_16x16x32_bf16(af[m], bfr[n], acc[m][n], 0, 0, 0);

        __syncthreads();
    }

    int r0 = m0 + wr * 64 + kb * 4;
    int c0 = n0 + wc * 64 + l15;
    #pragma unroll
    for (int m = 0; m < 4; ++m)
        #pragma unroll
        for (int n = 0; n < 4; ++n) {
            int rr = r0 + m * 16;
            int cc = c0 + n * 16;
            #pragma unroll
            for (int r = 0; r < 4; ++r)
                C[(size_t)(rr + r) * N + cc] = acc[m][n][r];
        }
}

// ---------------- Generic tiled fp32 GEMM: C = act(A @ W^T + bias) ----------------
__global__ __launch_bounds__(256) void gemm_nt(const float* __restrict__ A, int lda,
                                               const float* __restrict__ W, int ldw,
                                               float* __restrict__ C, int ldc,
                                               int N, int K,
                                               const float* __restrict__ bias, int act)
{
    __shared__ float As[64][17];
    __shared__ float Ws[64][17];
    int tid = threadIdx.x;
    int tx = tid & 15;
    int ty = tid >> 4;
    int m0 = blockIdx.y * 64;
    int n0 = blockIdx.x * 64;

    float acc[4][4] = {};

    for (int k0 = 0; k0 < K; k0 += 16) {
        #pragma unroll
        for (int i = 0; i < 4; ++i) {
            int idx = tid + i * 256;
            int r = idx >> 4, c = idx & 15;
            As[r][c] = A[(size_t)(m0 + r) * lda + k0 + c];
            int nr = n0 + r;
            Ws[r][c] = (nr < N) ? W[(size_t)nr * ldw + k0 + c] : 0.f;
        }
        __syncthreads();
        #pragma unroll
        for (int kk = 0; kk < 16; ++kk) {
            float av[4], wv[4];
            #pragma unroll
            for (int i = 0; i < 4; ++i) av[i] = As[ty * 4 + i][kk];
            #pragma unroll
            for (int j = 0; j < 4; ++j) wv[j] = Ws[tx * 4 + j][kk];
            #pragma unroll
            for (int i = 0; i < 4; ++i)
                #pragma unroll
                for (int j = 0; j < 4; ++j)
                    acc[i][j] += av[i] * wv[j];
        }
        __syncthreads();
    }

    #pragma unroll
    for (int i = 0; i < 4; ++i) {
        int m = m0 + ty * 4 + i;
        #pragma unroll
        for (int j = 0; j < 4; ++j) {
            int n = n0 + tx * 4 + j;
            if (n < N) {
                float v = acc[i][j];
                if (bias) v += bias[n];
                if (act == 1) v = (v > 20.f) ? v : log1pf(__expf(v));
                C[(size_t)m * ldc + n] = v;
            }
        }
    }
}

// ---- split-K fp32 GEMM: Cpart[z] = A @ W^T over K-slice z (no bias/act) ----
__global__ __launch_bounds__(256) void gemm_nt_sk(const float* __restrict__ A, int lda,
                                                  const float* __restrict__ W, int ldw,
                                                  float* __restrict__ Cpart, int ldc,
                                                  int N, int Kslice, int M)
{
    __shared__ float As[64][17];
    __shared__ float Ws[64][17];
    int tid = threadIdx.x;
    int tx = tid & 15;
    int ty = tid >> 4;
    int m0 = blockIdx.y * 64;
    int n0 = blockIdx.x * 64;
    int kbase = blockIdx.z * Kslice;
    float* C = Cpart + (size_t)blockIdx.z * M * ldc;

    float acc[4][4] = {};

    for (int k0 = kbase; k0 < kbase + Kslice; k0 += 16) {
        #pragma unroll
        for (int i = 0; i < 4; ++i) {
            int idx = tid + i * 256;
            int r = idx >> 4, c = idx & 15;
            As[r][c] = A[(size_t)(m0 + r) * lda + k0 + c];
            int nr = n0 + r;
            Ws[r][c] = (nr < N) ? W[(size_t)nr * ldw + k0 + c] : 0.f;
        }
        __syncthreads();
        #pragma unroll
        for (int kk = 0; kk < 16; ++kk) {
            float av[4], wv[4];
            #pragma unroll
            for (int i = 0; i < 4; ++i) av[i] = As[ty * 4 + i][kk];
            #pragma unroll
            for (int j = 0; j < 4; ++j) wv[j] = Ws[tx * 4 + j][kk];
            #pragma unroll
            for (int i = 0; i < 4; ++i)
                #pragma unroll
                for (int j = 0; j < 4; ++j)
                    acc[i][j] += av[i] * wv[j];
        }
        __syncthreads();
    }

    #pragma unroll
    for (int i = 0; i < 4; ++i) {
        int m = m0 + ty * 4 + i;
        #pragma unroll
        for (int j = 0; j < 4; ++j) {
            int n = n0 + tx * 4 + j;
            if (n < N)
                C[(size_t)m * ldc + n] = acc[i][j];
        }
    }
}

// ---------------- causal depthwise conv + SiLU ----------------
__global__ __launch_bounds__(256) void conv_silu_kernel(const float* __restrict__ xz,
                                                        const float* __restrict__ cw,
                                                        const float* __restrict__ cb,
                                                        float* __restrict__ u)
{
    int idx = blockIdx.x * 256 + threadIdx.x;
    int d = idx % DI;
    int t = (idx / DI) % SEQ;
    int b = idx / (DI * SEQ);

    float acc = cb[d];
    #pragma unroll
    for (int k = 0; k < DCONV; ++k) {
        int tt = t - (DCONV - 1) + k;
        if (tt >= 0) acc += xz[(size_t)(b * SEQ + tt) * XZW + d] * cw[d * DCONV + k];
    }
    u[(size_t)(b * SEQ + t) * DI + d] = acc * sigmoidf_(acc);
}

// ---------------- chunked parallel selective scan + gate (bf16 y out) -------------
// XCD-aware block swizzle: 3072 blocks, 8 XCDs, 384 contiguous (b,d) per XCD so each
// 64B line of the strided column reads/writes is owned by exactly one XCD L2.
__global__ __launch_bounds__(256) void scan_kernel(const float* __restrict__ delta,
                                                   const float* __restrict__ u,
                                                   const float* __restrict__ dbc,
                                                   const float* __restrict__ xz,
                                                   const float* __restrict__ A_log,
                                                   const float* __restrict__ Dp,
                                                   ushort_t* __restrict__ y)
{
    __shared__ float dl_s[SEQ];
    __shared__ float uu_s[SEQ];
    __shared__ float Ps[DS][NCHUNK + 1];
    __shared__ float Ss[DS][NCHUNK + 1];
    __shared__ float Hin[DS][NCHUNK + 1];

    int tid = threadIdx.x;
    int n = tid & 15;
    int chunk = tid >> 4;
    int p_ = blockIdx.x;
    int g = (p_ & 7) * (BATCH * DI / 8) + (p_ >> 3);   // XCD-contiguous mapping
    int b = g / DI;
    int d = g % DI;

    const float* drow = delta + (size_t)b * SEQ * DI + d;
    const float* urow = u     + (size_t)b * SEQ * DI + d;
    const float* bc   = dbc   + (size_t)b * SEQ * DBCW;
    const float* zrow = xz    + (size_t)b * SEQ * XZW + DI + d;
    ushort_t* yrow    = y     + (size_t)b * SEQ * DI + d;

    #pragma unroll
    for (int i = 0; i < SEQ / 256; ++i) {
        int t = tid + i * 256;
        dl_s[t] = drow[(size_t)t * DI];
        uu_s[t] = urow[(size_t)t * DI];
    }

    // fold log2(e) into a so dA = exp2(dlt * a) is a single v_exp_f32
    float a = -__expf(A_log[d * DS + n]) * 1.44269504f;
    int t0 = chunk * CLEN;
    __syncthreads();

    // Phase 1: chunk-local (P,S), h_in = 0
    float P = 1.f, S = 0.f;
    for (int t = t0; t < t0 + CLEN; ++t) {
        float dlt = dl_s[t];
        float Bv  = bc[(size_t)t * DBCW + DTR + n];
        float dA  = exp2f(dlt * a);
        P *= dA;
        S = dA * S + (dlt * uu_s[t]) * Bv;
    }
    Ps[n][chunk] = P;
    Ss[n][chunk] = S;
    __syncthreads();

    // Phase 2: serial chunk combine
    if (tid < DS) {
        float h = 0.f;
        #pragma unroll
        for (int c = 0; c < NCHUNK; ++c) {
            Hin[tid][c] = h;
            h = Ps[tid][c] * h + Ss[tid][c];
        }
    }
    __syncthreads();

    // Phase 3: replay with correct h_in, contract C, gate, write bf16
    float h = Hin[n][chunk];
    float Dd = Dp[d];
    for (int t = t0; t < t0 + CLEN; ++t) {
        float dlt = dl_s[t];
        float uu  = uu_s[t];
        float Bv  = bc[(size_t)t * DBCW + DTR + n];
        float Cv  = bc[(size_t)t * DBCW + DTR + DS + n];
        float dA  = exp2f(dlt * a);
        h = dA * h + (dlt * uu) * Bv;
        float p = h * Cv;
        p += __shfl_xor(p, 8);
        p += __shfl_xor(p, 4);
        p += __shfl_xor(p, 2);
        p += __shfl_xor(p, 1);
        if (n == 0) {
            float z = zrow[(size_t)t * XZW];
            float yv = (p + uu * Dd) * (z * sigmoidf_(z));
            yrow[(size_t)t * DI] = f2bf(yv);
        }
    }
}

extern "C" void kernel_launch(void* const* d_in, const int* in_sizes, int n_in,
                              void* d_out, int out_size, void* d_ws, size_t ws_size,
                              hipStream_t stream) {
    const float* x         = (const float*)d_in[0];
    const float* ln_w      = (const float*)d_in[1];
    const float* ln_b      = (const float*)d_in[2];
    const float* in_proj_w = (const float*)d_in[3];   // (3072, 768)
    const float* conv_w    = (const float*)d_in[4];   // (1536, 4)
    const float* conv_b    = (const float*)d_in[5];   // (1536)
    const float* x_proj_w  = (const float*)d_in[6];   // (80, 1536)
    const float* dt_proj_w = (const float*)d_in[7];   // (1536, 48)
    const float* dt_proj_b = (const float*)d_in[8];   // (1536)
    const float* A_log     = (const float*)d_in[9];   // (1536, 16)
    const float* D_param   = (const float*)d_in[10];  // (1536)
    const float* out_proj_w= (const float*)d_in[11];  // (768, 1536)
    float* out = (float*)d_out;

    char* ws = (char*)d_ws;
    size_t off = 0;
    auto alloc = [&](size_t bytes) { void* p = ws + off; off += (bytes + 255) & ~255ull; return p; };

    ushort_t* xn_bf   = (ushort_t*)alloc((size_t)MROWS * DIM * 2);
    ushort_t* w_in_bf = (ushort_t*)alloc((size_t)XZW * DIM * 2);
    ushort_t* w_out_bf= (ushort_t*)alloc((size_t)DIM * DI * 2);
    ushort_t* y_bf    = (ushort_t*)alloc((size_t)MROWS * DI * 2);
    float* xz    = (float*)alloc((size_t)MROWS * XZW * 4);
    float* u     = (float*)alloc((size_t)MROWS * DI * 4);
    float* dbc   = (float*)alloc((size_t)MROWS * DBCW * 4);
    float* delta = (float*)alloc((size_t)MROWS * DI * 4);
    float* xpart = (float*)alloc((size_t)XP_KS * MROWS * DBCW * 4);
    float* opart = (float*)alloc((size_t)OP_KS * MROWS * DIM * 4);

    // 0. weight conversions
    hipLaunchKernelGGL(cvt_bf16, dim3((XZW * DIM) / 2048), dim3(256), 0, stream,
                       in_proj_w, w_in_bf, XZW * DIM);
    hipLaunchKernelGGL(cvt_bf16, dim3((DIM * DI) / 2048), dim3(256), 0, stream,
                       out_proj_w, w_out_bf, DIM * DI);

    // 1. LayerNorm -> bf16
    hipLaunchKernelGGL(ln_kernel, dim3(MROWS), dim3(256), 0, stream, x, ln_w, ln_b, xn_bf);

    // 2. in_proj (bf16 MFMA): xz(2048x3072) = xn @ in_proj_w^T
    hipLaunchKernelGGL(gemm_bf16, dim3(XZW / 128, MROWS / 128), dim3(256), 0, stream,
                       xn_bf, w_in_bf, xz, XZW, DIM);

    // 3. conv + silu -> u (fp32)
    hipLaunchKernelGGL(conv_silu_kernel, dim3((MROWS * DI) / 256), dim3(256), 0, stream,
                       xz, conv_w, conv_b, u);

    // 4. x_proj (fp32 split-K): dbc(2048x80) = u @ x_proj_w^T
    hipLaunchKernelGGL(gemm_nt_sk, dim3((DBCW + 63) / 64, MROWS / 64, XP_KS), dim3(256), 0, stream,
                       u, DI, x_proj_w, DI, xpart, DBCW, DBCW, DI / XP_KS, MROWS);
    hipLaunchKernelGGL(reduce_sk4, dim3((MROWS * DBCW / 4 + 255) / 256), dim3(256), 0, stream,
                       (const float4*)xpart, (float4*)dbc, MROWS * DBCW / 4, XP_KS);

    // 5. dt_proj + softplus (fp32): delta = softplus(dbc[:, :48] @ dt_proj_w^T + b)
    hipLaunchKernelGGL(gemm_nt, dim3(DI / 64, MROWS / 64), dim3(256), 0, stream,
                       dbc, DBCW, dt_proj_w, DTR, delta, DI, DI, DTR, dt_proj_b, 1);

    // 6. chunked scan + gate -> y (bf16), XCD-swizzled
    hipLaunchKernelGGL(scan_kernel, dim3(BATCH * DI), dim3(256), 0, stream,
                       delta, u, dbc, xz, A_log, D_param, y_bf);

    // 7. out_proj (bf16 MFMA split-K): out(2048x768) = y @ out_proj_w^T
    hipLaunchKernelGGL(gemm_bf16_sk, dim3(DIM / 128, MROWS / 128, OP_KS), dim3(256), 0, stream,
                       y_bf, w_out_bf, opart, DIM, DI, DI / OP_KS, MROWS);
    hipLaunchKernelGGL(reduce_sk4, dim3((MROWS * DIM / 4 + 255) / 256), dim3(256), 0, stream,
                       (const float4*)opart, (float4*)out, MROWS * DIM / 4, OP_KS);
}

// Round 6
// 229.575 us; speedup vs baseline: 6.0264x; 1.1234x over previous
//
#include <hip/hip_runtime.h>
#include <hip/hip_bf16.h>

// Mamba layer: LN -> in_proj(bf16 MFMA) -> conv+silu -> x_proj(fp32 split-K)
//              -> dt_proj+softplus -> chunked scan+gate (XCD-swizzled) -> out_proj(bf16 MFMA split-K)
#define BATCH 2
#define SEQ   1024
#define DIM   768
#define DI    1536
#define DS    16
#define DCONV 4
#define DTR   48
#define XZW   (2*DI)     // 3072
#define DBCW  (DTR+2*DS) // 80
#define MROWS (BATCH*SEQ) // 2048
#define NCHUNK 16
#define CLEN  (SEQ/NCHUNK) // 64
#define XP_KS 8          // x_proj split-K slices
#define OP_KS 4          // out_proj split-K slices
#define PIDX(t) ((t) + ((t) >> 6))   // chunk-pad: spreads the 4 chunk-groups across banks

typedef unsigned short ushort_t;
typedef __attribute__((ext_vector_type(8))) short short8;
typedef __attribute__((ext_vector_type(4))) float f32x4;

__device__ __forceinline__ float sigmoidf_(float x) {
    return 1.f / (1.f + __expf(-x));
}

__device__ __forceinline__ ushort_t f2bf(float x) {
    union { float f; unsigned u; } c{x};
    unsigned r = c.u + 0x7FFF + ((c.u >> 16) & 1);   // RNE
    return (ushort_t)(r >> 16);
}

__device__ __forceinline__ void gload16(const void* g, void* lds) {
    __builtin_amdgcn_global_load_lds(
        (const __attribute__((address_space(1))) void*)g,
        (__attribute__((address_space(3))) void*)lds,
        16, 0, 0);
}

// ---------------- fp32 -> bf16 conversion (8 elems/thread) ----------------
__global__ __launch_bounds__(256) void cvt_bf16(const float* __restrict__ in,
                                                ushort_t* __restrict__ out, int n)
{
    int i = (blockIdx.x * 256 + threadIdx.x) * 8;
    if (i >= n) return;
    float4 a = *(const float4*)(in + i);
    float4 b = *(const float4*)(in + i + 4);
    ushort_t o[8] = { f2bf(a.x), f2bf(a.y), f2bf(a.z), f2bf(a.w),
                      f2bf(b.x), f2bf(b.y), f2bf(b.z), f2bf(b.w) };
    *(ushort4*)(out + i)     = *(ushort4*)o;
    *(ushort4*)(out + i + 4) = *(ushort4*)(o + 4);
}

// ---------------- split-K partial reduce: out[i] = sum_z part[z][i] (float4) -------
__global__ __launch_bounds__(256) void reduce_sk4(const float4* __restrict__ part,
                                                  float4* __restrict__ out,
                                                  int count4, int nslices)
{
    int i = blockIdx.x * 256 + threadIdx.x;
    if (i >= count4) return;
    float4 s = part[i];
    for (int z = 1; z < nslices; ++z) {
        float4 p = part[(size_t)z * count4 + i];
        s.x += p.x; s.y += p.y; s.z += p.z; s.w += p.w;
    }
    out[i] = s;
}

// ---------------- LayerNorm (fp32 in, bf16 out), shfl-based ----------------
__global__ __launch_bounds__(256) void ln_kernel(const float* __restrict__ x,
                                                 const float* __restrict__ w,
                                                 const float* __restrict__ b,
                                                 ushort_t* __restrict__ xn)
{
    __shared__ float part[8];
    int row = blockIdx.x;               // 0..2047
    const float* xr = x + (size_t)row * DIM;
    ushort_t* o = xn + (size_t)row * DIM;
    int tid = threadIdx.x;
    int lane = tid & 63, wid = tid >> 6;

    float v0 = xr[tid], v1 = xr[tid + 256], v2 = xr[tid + 512];
    float s = v0 + v1 + v2;
    #pragma unroll
    for (int off = 32; off > 0; off >>= 1) s += __shfl_xor(s, off);
    if (lane == 0) part[wid] = s;
    __syncthreads();
    float mu = (part[0] + part[1] + part[2] + part[3]) * (1.f / DIM);

    float d0 = v0 - mu, d1 = v1 - mu, d2 = v2 - mu;
    float q = d0 * d0 + d1 * d1 + d2 * d2;
    #pragma unroll
    for (int off = 32; off > 0; off >>= 1) q += __shfl_xor(q, off);
    if (lane == 0) part[4 + wid] = q;
    __syncthreads();
    float rstd = rsqrtf((part[4] + part[5] + part[6] + part[7]) * (1.f / DIM) + 1e-5f);

    o[tid]       = f2bf(d0 * rstd * w[tid]       + b[tid]);
    o[tid + 256] = f2bf(d1 * rstd * w[tid + 256] + b[tid + 256]);
    o[tid + 512] = f2bf(d2 * rstd * w[tid + 512] + b[tid + 512]);
}

// ---------------- bf16 MFMA GEMM: C(MxN fp32) = A(MxK bf16) @ W(NxK bf16)^T ----------
__global__ __launch_bounds__(256) void gemm_bf16(const ushort_t* __restrict__ A,
                                                 const ushort_t* __restrict__ W,
                                                 float* __restrict__ C,
                                                 int N, int K)
{
    __shared__ __align__(16) ushort_t As[128 * 32];
    __shared__ __align__(16) ushort_t Bs[128 * 32];

    int tid = threadIdx.x;
    int wave = tid >> 6, lane = tid & 63;
    int wr = wave >> 1, wc = wave & 1;
    int l15 = lane & 15, kb = lane >> 4;
    int m0 = blockIdx.y * 128, n0 = blockIdx.x * 128;

    f32x4 acc[4][4] = {};

    for (int k0 = 0; k0 < K; k0 += 32) {
        #pragma unroll
        for (int i = 0; i < 2; ++i) {
            int cbase = i * 256 + wave * 64;
            int c = cbase + lane;
            int row = c >> 2;
            int col = (c & 3) * 8;
            gload16(A + (size_t)(m0 + row) * K + k0 + col, (char*)As + (size_t)cbase * 16);
            gload16(W + (size_t)(n0 + row) * K + k0 + col, (char*)Bs + (size_t)cbase * 16);
        }
        __syncthreads();

        short8 af[4], bfr[4];
        #pragma unroll
        for (int m = 0; m < 4; ++m)
            af[m] = *(const short8*)&As[(wr * 64 + m * 16 + l15) * 32 + kb * 8];
        #pragma unroll
        for (int n = 0; n < 4; ++n)
            bfr[n] = *(const short8*)&Bs[(wc * 64 + n * 16 + l15) * 32 + kb * 8];

        #pragma unroll
        for (int m = 0; m < 4; ++m)
            #pragma unroll
            for (int n = 0; n < 4; ++n)
                acc[m][n] = __builtin_amdgcn_mfma_f32_16x16x32_bf16(af[m], bfr[n], acc[m][n], 0, 0, 0);

        __syncthreads();
    }

    int r0 = m0 + wr * 64 + kb * 4;
    int c0 = n0 + wc * 64 + l15;
    #pragma unroll
    for (int m = 0; m < 4; ++m)
        #pragma unroll
        for (int n = 0; n < 4; ++n) {
            int rr = r0 + m * 16;
            int cc = c0 + n * 16;
            #pragma unroll
            for (int r = 0; r < 4; ++r)
                C[(size_t)(rr + r) * N + cc] = acc[m][n][r];
        }
}

// ---- split-K bf16 MFMA GEMM: Cpart[z] = A @ W^T over K-slice z (z = blockIdx.z) ----
__global__ __launch_bounds__(256) void gemm_bf16_sk(const ushort_t* __restrict__ A,
                                                    const ushort_t* __restrict__ W,
                                                    float* __restrict__ Cpart,
                                                    int N, int Ktot, int Kslice, int M)
{
    __shared__ __align__(16) ushort_t As[128 * 32];
    __shared__ __align__(16) ushort_t Bs[128 * 32];

    int tid = threadIdx.x;
    int wave = tid >> 6, lane = tid & 63;
    int wr = wave >> 1, wc = wave & 1;
    int l15 = lane & 15, kb = lane >> 4;
    int m0 = blockIdx.y * 128, n0 = blockIdx.x * 128;
    int kbase = blockIdx.z * Kslice;
    float* C = Cpart + (size_t)blockIdx.z * M * N;

    f32x4 acc[4][4] = {};

    for (int k0 = kbase; k0 < kbase + Kslice; k0 += 32) {
        #pragma unroll
        for (int i = 0; i < 2; ++i) {
            int cbase = i * 256 + wave * 64;
            int c = cbase + lane;
            int row = c >> 2;
            int col = (c & 3) * 8;
            gload16(A + (size_t)(m0 + row) * Ktot + k0 + col, (char*)As + (size_t)cbase * 16);
            gload16(W + (size_t)(n0 + row) * Ktot + k0 + col, (char*)Bs + (size_t)cbase * 16);
        }
        __syncthreads();

        short8 af[4], bfr[4];
        #pragma unroll
        for (int m = 0; m < 4; ++m)
            af[m] = *(const short8*)&As[(wr * 64 + m * 16 + l15) * 32 + kb * 8];
        #pragma unroll
        for (int n = 0; n < 4; ++n)
            bfr[n] = *(const short8*)&Bs[(wc * 64 + n * 16 + l15) * 32 + kb * 8];

        #pragma unroll
        for (int m = 0; m < 4; ++m)
            #pragma unroll
            for (int n = 0; n < 4; ++n)
                acc[m][n] = __builtin_amdgcn_mfma_f32_16x16x32_bf16(af[m], bfr[n], acc[m][n], 0, 0, 0);

        __syncthreads();
    }

    int r0 = m0 + wr * 64 + kb * 4;
    int c0 = n0 + wc * 64 + l15;
    #pragma unroll
    for (int m = 0; m < 4; ++m)
        #pragma unroll
        for (int n = 0; n < 4; ++n) {
            int rr = r0 + m * 16;
            int cc = c0 + n * 16;
            #pragma unroll
            for (int r = 0; r < 4; ++r)
                C[(size_t)(rr + r) * N + cc] = acc[m][n][r];
        }
}

// ---------------- Generic tiled fp32 GEMM: C = act(A @ W^T + bias) ----------------
__global__ __launch_bounds__(256) void gemm_nt(const float* __restrict__ A, int lda,
                                               const float* __restrict__ W, int ldw,
                                               float* __restrict__ C, int ldc,
                                               int N, int K,
                                               const float* __restrict__ bias, int act)
{
    __shared__ float As[64][17];
    __shared__ float Ws[64][17];
    int tid = threadIdx.x;
    int tx = tid & 15;
    int ty = tid >> 4;
    int m0 = blockIdx.y * 64;
    int n0 = blockIdx.x * 64;

    float acc[4][4] = {};

    for (int k0 = 0; k0 < K; k0 += 16) {
        #pragma unroll
        for (int i = 0; i < 4; ++i) {
            int idx = tid + i * 256;
            int r = idx >> 4, c = idx & 15;
            As[r][c] = A[(size_t)(m0 + r) * lda + k0 + c];
            int nr = n0 + r;
            Ws[r][c] = (nr < N) ? W[(size_t)nr * ldw + k0 + c] : 0.f;
        }
        __syncthreads();
        #pragma unroll
        for (int kk = 0; kk < 16; ++kk) {
            float av[4], wv[4];
            #pragma unroll
            for (int i = 0; i < 4; ++i) av[i] = As[ty * 4 + i][kk];
            #pragma unroll
            for (int j = 0; j < 4; ++j) wv[j] = Ws[tx * 4 + j][kk];
            #pragma unroll
            for (int i = 0; i < 4; ++i)
                #pragma unroll
                for (int j = 0; j < 4; ++j)
                    acc[i][j] += av[i] * wv[j];
        }
        __syncthreads();
    }

    #pragma unroll
    for (int i = 0; i < 4; ++i) {
        int m = m0 + ty * 4 + i;
        #pragma unroll
        for (int j = 0; j < 4; ++j) {
            int n = n0 + tx * 4 + j;
            if (n < N) {
                float v = acc[i][j];
                if (bias) v += bias[n];
                if (act == 1) v = (v > 20.f) ? v : log1pf(__expf(v));
                C[(size_t)m * ldc + n] = v;
            }
        }
    }
}

// ---- split-K fp32 GEMM: Cpart[z] = A @ W^T over K-slice z (no bias/act) ----
__global__ __launch_bounds__(256) void gemm_nt_sk(const float* __restrict__ A, int lda,
                                                  const float* __restrict__ W, int ldw,
                                                  float* __restrict__ Cpart, int ldc,
                                                  int N, int Kslice, int M)
{
    __shared__ float As[64][17];
    __shared__ float Ws[64][17];
    int tid = threadIdx.x;
    int tx = tid & 15;
    int ty = tid >> 4;
    int m0 = blockIdx.y * 64;
    int n0 = blockIdx.x * 64;
    int kbase = blockIdx.z * Kslice;
    float* C = Cpart + (size_t)blockIdx.z * M * ldc;

    float acc[4][4] = {};

    for (int k0 = kbase; k0 < kbase + Kslice; k0 += 16) {
        #pragma unroll
        for (int i = 0; i < 4; ++i) {
            int idx = tid + i * 256;
            int r = idx >> 4, c = idx & 15;
            As[r][c] = A[(size_t)(m0 + r) * lda + k0 + c];
            int nr = n0 + r;
            Ws[r][c] = (nr < N) ? W[(size_t)nr * ldw + k0 + c] : 0.f;
        }
        __syncthreads();
        #pragma unroll
        for (int kk = 0; kk < 16; ++kk) {
            float av[4], wv[4];
            #pragma unroll
            for (int i = 0; i < 4; ++i) av[i] = As[ty * 4 + i][kk];
            #pragma unroll
            for (int j = 0; j < 4; ++j) wv[j] = Ws[tx * 4 + j][kk];
            #pragma unroll
            for (int i = 0; i < 4; ++i)
                #pragma unroll
                for (int j = 0; j < 4; ++j)
                    acc[i][j] += av[i] * wv[j];
        }
        __syncthreads();
    }

    #pragma unroll
    for (int i = 0; i < 4; ++i) {
        int m = m0 + ty * 4 + i;
        #pragma unroll
        for (int j = 0; j < 4; ++j) {
            int n = n0 + tx * 4 + j;
            if (n < N)
                C[(size_t)m * ldc + n] = acc[i][j];
        }
    }
}

// ---------------- causal depthwise conv + SiLU (float4 over d) ----------------
__global__ __launch_bounds__(256) void conv_silu_kernel(const float* __restrict__ xz,
                                                        const float* __restrict__ cw,
                                                        const float* __restrict__ cb,
                                                        float* __restrict__ u)
{
    int idx = blockIdx.x * 256 + threadIdx.x;   // over MROWS * DI/4
    int d4 = idx % (DI / 4);
    int bt = idx / (DI / 4);
    int t = bt % SEQ;
    int b = bt / SEQ;
    int d = d4 * 4;

    // weights for 4 consecutive channels: cw[(d+j)*4 + k]
    float4 w0 = *(const float4*)(cw + (d + 0) * 4);
    float4 w1 = *(const float4*)(cw + (d + 1) * 4);
    float4 w2 = *(const float4*)(cw + (d + 2) * 4);
    float4 w3 = *(const float4*)(cw + (d + 3) * 4);
    const float* wp[4] = { (const float*)&w0, (const float*)&w1,
                           (const float*)&w2, (const float*)&w3 };

    float4 acc = *(const float4*)(cb + d);
    #pragma unroll
    for (int k = 0; k < DCONV; ++k) {
        int tt = t - (DCONV - 1) + k;
        if (tt >= 0) {
            float4 xv = *(const float4*)(xz + (size_t)(b * SEQ + tt) * XZW + d);
            acc.x += xv.x * wp[0][k];
            acc.y += xv.y * wp[1][k];
            acc.z += xv.z * wp[2][k];
            acc.w += xv.w * wp[3][k];
        }
    }
    acc.x *= sigmoidf_(acc.x);
    acc.y *= sigmoidf_(acc.y);
    acc.z *= sigmoidf_(acc.z);
    acc.w *= sigmoidf_(acc.w);
    *(float4*)(u + (size_t)(b * SEQ + t) * DI + d) = acc;
}

// ---------------- chunked parallel selective scan + gate (bf16 y out) -------------
// One block per (b,d), XCD-swizzled. Threads = (chunk 0..15) x (n 0..15).
// LDS: (delta,u) packed float2 with chunk padding (conflict-free b64 reads);
// SiLU(z) gates precomputed at full lane parallelism.
__global__ __launch_bounds__(256) void scan_kernel(const float* __restrict__ delta,
                                                   const float* __restrict__ u,
                                                   const float* __restrict__ dbc,
                                                   const float* __restrict__ xz,
                                                   const float* __restrict__ A_log,
                                                   const float* __restrict__ Dp,
                                                   ushort_t* __restrict__ y)
{
    __shared__ float2 du_s[SEQ + NCHUNK];      // packed (delta, u), padded
    __shared__ float  g_s[SEQ + NCHUNK];       // silu(z) gate, padded
    __shared__ float Ps[DS][NCHUNK + 1];
    __shared__ float Ss[DS][NCHUNK + 1];
    __shared__ float Hin[DS][NCHUNK + 1];

    int tid = threadIdx.x;
    int n = tid & 15;
    int chunk = tid >> 4;
    int p_ = blockIdx.x;
    int g = (p_ & 7) * (BATCH * DI / 8) + (p_ >> 3);   // XCD-contiguous mapping
    int b = g / DI;
    int d = g % DI;

    const float* drow = delta + (size_t)b * SEQ * DI + d;
    const float* urow = u     + (size_t)b * SEQ * DI + d;
    const float* bc   = dbc   + (size_t)b * SEQ * DBCW;
    const float* zrow = xz    + (size_t)b * SEQ * XZW + DI + d;

    // stage: (delta,u) pairs + precomputed gates, each global elem read once
    #pragma unroll
    for (int i = 0; i < SEQ / 256; ++i) {
        int t = tid + i * 256;
        du_s[PIDX(t)] = make_float2(drow[(size_t)t * DI], urow[(size_t)t * DI]);
        float z = zrow[(size_t)t * XZW];
        g_s[PIDX(t)] = z * sigmoidf_(z);
    }

    // fold log2(e) into a so dA = exp2(dlt * a) is a single v_exp_f32
    float a = -__expf(A_log[d * DS + n]) * 1.44269504f;
    int t0 = chunk * CLEN;
    __syncthreads();

    // Phase 1: chunk-local (P,S), h_in = 0
    float P = 1.f, S = 0.f;
    {
        const float* bp = bc + (size_t)t0 * DBCW + DTR + n;
        #pragma unroll 4
        for (int i = 0; i < CLEN; ++i, bp += DBCW) {
            float2 du = du_s[PIDX(t0 + i)];
            float dA = exp2f(du.x * a);
            P *= dA;
            S = dA * S + (du.x * du.y) * (*bp);
        }
    }
    Ps[n][chunk] = P;
    Ss[n][chunk] = S;
    __syncthreads();

    // Phase 2: serial chunk combine (16 threads x 16 steps)
    if (tid < DS) {
        float h = 0.f;
        #pragma unroll
        for (int c = 0; c < NCHUNK; ++c) {
            Hin[tid][c] = h;
            h = Ps[tid][c] * h + Ss[tid][c];
        }
    }
    __syncthreads();

    // Phase 3: replay with correct h_in, contract C, gate, write bf16
    float h = Hin[n][chunk];
    float Dd = Dp[d];
    {
        const float* bp = bc + (size_t)t0 * DBCW + DTR + n;
        ushort_t* yp = y + (size_t)b * SEQ * DI + (size_t)t0 * DI + d;
        #pragma unroll 4
        for (int i = 0; i < CLEN; ++i, bp += DBCW, yp += DI) {
            float2 du = du_s[PIDX(t0 + i)];
            float Bv = bp[0];
            float Cv = bp[DS];
            float dA = exp2f(du.x * a);
            h = dA * h + (du.x * du.y) * Bv;
            float p = h * Cv;
            p += __shfl_xor(p, 8);
            p += __shfl_xor(p, 4);
            p += __shfl_xor(p, 2);
            p += __shfl_xor(p, 1);
            if (n == 0)
                *yp = f2bf((p + du.y * Dd) * g_s[PIDX(t0 + i)]);
        }
    }
}

extern "C" void kernel_launch(void* const* d_in, const int* in_sizes, int n_in,
                              void* d_out, int out_size, void* d_ws, size_t ws_size,
                              hipStream_t stream) {
    const float* x         = (const float*)d_in[0];
    const float* ln_w      = (const float*)d_in[1];
    const float* ln_b      = (const float*)d_in[2];
    const float* in_proj_w = (const float*)d_in[3];   // (3072, 768)
    const float* conv_w    = (const float*)d_in[4];   // (1536, 4)
    const float* conv_b    = (const float*)d_in[5];   // (1536)
    const float* x_proj_w  = (const float*)d_in[6];   // (80, 1536)
    const float* dt_proj_w = (const float*)d_in[7];   // (1536, 48)
    const float* dt_proj_b = (const float*)d_in[8];   // (1536)
    const float* A_log     = (const float*)d_in[9];   // (1536, 16)
    const float* D_param   = (const float*)d_in[10];  // (1536)
    const float* out_proj_w= (const float*)d_in[11];  // (768, 1536)
    float* out = (float*)d_out;

    char* ws = (char*)d_ws;
    size_t off = 0;
    auto alloc = [&](size_t bytes) { void* p = ws + off; off += (bytes + 255) & ~255ull; return p; };

    ushort_t* xn_bf   = (ushort_t*)alloc((size_t)MROWS * DIM * 2);
    ushort_t* w_in_bf = (ushort_t*)alloc((size_t)XZW * DIM * 2);
    ushort_t* w_out_bf= (ushort_t*)alloc((size_t)DIM * DI * 2);
    ushort_t* y_bf    = (ushort_t*)alloc((size_t)MROWS * DI * 2);
    float* xz    = (float*)alloc((size_t)MROWS * XZW * 4);
    float* u     = (float*)alloc((size_t)MROWS * DI * 4);
    float* dbc   = (float*)alloc((size_t)MROWS * DBCW * 4);
    float* delta = (float*)alloc((size_t)MROWS * DI * 4);
    float* xpart = (float*)alloc((size_t)XP_KS * MROWS * DBCW * 4);
    float* opart = (float*)alloc((size_t)OP_KS * MROWS * DIM * 4);

    // 0. weight conversions
    hipLaunchKernelGGL(cvt_bf16, dim3((XZW * DIM) / 2048), dim3(256), 0, stream,
                       in_proj_w, w_in_bf, XZW * DIM);
    hipLaunchKernelGGL(cvt_bf16, dim3((DIM * DI) / 2048), dim3(256), 0, stream,
                       out_proj_w, w_out_bf, DIM * DI);

    // 1. LayerNorm -> bf16
    hipLaunchKernelGGL(ln_kernel, dim3(MROWS), dim3(256), 0, stream, x, ln_w, ln_b, xn_bf);

    // 2. in_proj (bf16 MFMA): xz(2048x3072) = xn @ in_proj_w^T
    hipLaunchKernelGGL(gemm_bf16, dim3(XZW / 128, MROWS / 128), dim3(256), 0, stream,
                       xn_bf, w_in_bf, xz, XZW, DIM);

    // 3. conv + silu -> u (fp32, float4)
    hipLaunchKernelGGL(conv_silu_kernel, dim3((MROWS * DI / 4) / 256), dim3(256), 0, stream,
                       xz, conv_w, conv_b, u);

    // 4. x_proj (fp32 split-K): dbc(2048x80) = u @ x_proj_w^T
    hipLaunchKernelGGL(gemm_nt_sk, dim3((DBCW + 63) / 64, MROWS / 64, XP_KS), dim3(256), 0, stream,
                       u, DI, x_proj_w, DI, xpart, DBCW, DBCW, DI / XP_KS, MROWS);
    hipLaunchKernelGGL(reduce_sk4, dim3((MROWS * DBCW / 4 + 255) / 256), dim3(256), 0, stream,
                       (const float4*)xpart, (float4*)dbc, MROWS * DBCW / 4, XP_KS);

    // 5. dt_proj + softplus (fp32): delta = softplus(dbc[:, :48] @ dt_proj_w^T + b)
    hipLaunchKernelGGL(gemm_nt, dim3(DI / 64, MROWS / 64), dim3(256), 0, stream,
                       dbc, DBCW, dt_proj_w, DTR, delta, DI, DI, DTR, dt_proj_b, 1);

    // 6. chunked scan + gate -> y (bf16), XCD-swizzled
    hipLaunchKernelGGL(scan_kernel, dim3(BATCH * DI), dim3(256), 0, stream,
                       delta, u, dbc, xz, A_log, D_param, y_bf);

    // 7. out_proj (bf16 MFMA split-K): out(2048x768) = y @ out_proj_w^T
    hipLaunchKernelGGL(gemm_bf16_sk, dim3(DIM / 128, MROWS / 128, OP_KS), dim3(256), 0, stream,
                       y_bf, w_out_bf, opart, DIM, DI, DI / OP_KS, MROWS);
    hipLaunchKernelGGL(reduce_sk4, dim3((MROWS * DIM / 4 + 255) / 256), dim3(256), 0, stream,
                       (const float4*)opart, (float4*)out, MROWS * DIM / 4, OP_KS);
}